// Round 18
// baseline (830.510 us; speedup 1.0000x reference)
//
#include <hip/hip_runtime.h>
#include <hip/hip_bf16.h>

#define LSEQ 2048
#define NB 32

typedef __attribute__((ext_vector_type(8))) short short8v;
typedef __attribute__((ext_vector_type(4))) float float4v;

// ---------- dtype helpers ----------
__device__ __forceinline__ unsigned short f2b(float f){
  __hip_bfloat16 h = __float2bfloat16(f);
  return *reinterpret_cast<unsigned short*>(&h);
}
__device__ __forceinline__ float b2f_bits(unsigned short u){
  unsigned int x = ((unsigned int)u) << 16; return __uint_as_float(x);
}

__device__ __forceinline__ float wave_min(float v){
  #pragma unroll
  for (int off = 32; off; off >>= 1) v = fminf(v, __shfl_xor(v, off, 64));
  return v;
}

// apply BN(scale,shift)+relu to 8 bf16 packed in uint4, repack to bf16
__device__ __forceinline__ uint4 bn_pack(uint4 g, const float* sc, const float* sh, int cbase){
  union { uint4 u; unsigned short us[8]; } in_, out_;
  in_.u = g;
  #pragma unroll
  for (int j = 0; j < 8; ++j){
    float v = b2f_bits(in_.us[j]);
    v = fmaxf(fmaf(v, sc[cbase+j], sh[cbase+j]), 0.f);
    out_.us[j] = f2b(v);
  }
  return out_.u;
}

// async 16B global -> LDS
__device__ __forceinline__ void gl_lds16(const void* g, void* l){
  __builtin_amdgcn_global_load_lds(
      (const __attribute__((address_space(1))) void*)g,
      (__attribute__((address_space(3))) void*)l, 16, 0, 0);
}

// ---------- row preprocessing: stats + find_peaks + normalize ----------
__global__ __launch_bounds__(256)
void row_prep(const float* __restrict__ x, float* __restrict__ h0)
{
  const int b = blockIdx.x, tid = threadIdx.x;
  const int lane = tid & 63, wid = tid >> 6;
  __shared__ float xs_raw[LSEQ + 18];
  __shared__ unsigned char st_raw[LSEQ + 18];
  __shared__ unsigned char peaks[LSEQ];
  __shared__ short s_cand[1024];
  __shared__ short s_kept[256];
  __shared__ int s_flag, s_cnt, s_kcnt;
  __shared__ float s_redA[4], s_redB[4];
  __shared__ float s_mx, s_mean, s_std;
  float* xsp = xs_raw + 9;
  unsigned char* stp = st_raw + 9;

  const float* xr = x + (size_t)b * LSEQ;
  for (int i = tid; i < LSEQ; i += 256) xsp[i] = xr[i];
  for (int i = tid; i < 18; i += 256) {
    xs_raw[(i < 9) ? i : (LSEQ + i)] = -__builtin_inff();
    st_raw[(i < 9) ? i : (LSEQ + i)] = 2;
  }
  if (tid == 0) { s_cnt = 0; s_kcnt = 0; }
  __syncthreads();

  float vmax = -__builtin_inff(), vsum = 0.f;
  for (int i = tid; i < LSEQ; i += 256) { float v = xsp[i]; vmax = fmaxf(vmax, v); vsum += v; }
  #pragma unroll
  for (int off = 32; off; off >>= 1){
    vmax = fmaxf(vmax, __shfl_xor(vmax, off, 64));
    vsum += __shfl_xor(vsum, off, 64);
  }
  if (lane == 0){ s_redA[wid] = vmax; s_redB[wid] = vsum; }
  __syncthreads();
  if (tid == 0){
    s_mx   = fmaxf(fmaxf(s_redA[0], s_redA[1]), fmaxf(s_redA[2], s_redA[3]));
    s_mean = (s_redB[0]+s_redB[1]+s_redB[2]+s_redB[3]) * (1.f/(float)LSEQ);
  }
  __syncthreads();
  const float m = s_mean, mx = s_mx;

  float vss = 0.f;
  for (int i = tid; i < LSEQ; i += 256){ float d = xsp[i]-m; vss += d*d; }
  #pragma unroll
  for (int off = 32; off; off >>= 1) vss += __shfl_xor(vss, off, 64);
  if (lane == 0) s_redA[wid] = vss;
  __syncthreads();
  if (tid == 0) s_std = sqrtf((s_redA[0]+s_redA[1]+s_redA[2]+s_redA[3]) / (float)(LSEQ-1));
  __syncthreads();
  const float sd = s_std;

  const float hthr = 0.1f * mx;
  for (int i = tid; i < LSEQ; i += 256) {
    unsigned char c = 2;
    if (i >= 1 && i <= LSEQ-2) {
      float v = xsp[i];
      if ((v > xsp[i-1]) && (v > xsp[i+1]) && (v >= hthr)) {
        c = 0;
        int s = atomicAdd(&s_cnt, 1);
        if (s < 1024) s_cand[s] = (short)i;
      }
    }
    stp[i] = c; peaks[i] = 0;
  }
  __syncthreads();
  const int cnt = (s_cnt < 1024) ? s_cnt : 1024;

  for (int round = 0; round < 1024; ++round) {
    if (tid == 0) s_flag = 0;
    __syncthreads();
    int und = 0;
    for (int q = tid; q < cnt; q += 256) {
      int i = s_cand[q];
      if (stp[i] == 0) {
        float xi = xsp[i];
        bool anyK = false, allD = true;
        #pragma unroll
        for (int o = -9; o <= 9; ++o) {
          if (o == 0) continue;
          unsigned char s = stp[i+o];
          float xj = xsp[i+o];
          bool hi = (xj > xi) || (xj == xi && o < 0);
          anyK = anyK || (hi && s == 1);
          allD = allD && ((!hi) || s == 2);
        }
        unsigned char ns = anyK ? 2 : (allD ? 1 : 0);
        if (ns) stp[i] = ns; else und = 1;
      }
    }
    if (und) s_flag = 1;
    __syncthreads();
    if (!s_flag) break;
  }

  for (int q = tid; q < cnt; q += 256) {
    int i = s_cand[q];
    if (stp[i] == 1) { int s = atomicAdd(&s_kcnt, 1); s_kept[s] = (short)i; }
  }
  __syncthreads();
  const int M = s_kcnt;
  const float pthr = 0.05f * mx;

  for (int c = wid; c < M; c += 4) {
    int p = s_kept[c]; float xp = xsp[p];
    float lm = xp; bool done = false;
    for (int s = 0; !done; ++s) {
      int idx = p - 64*(s+1) + lane;
      float v = (idx >= 0) ? xsp[idx] : -__builtin_inff();
      unsigned long long mk = __ballot(v > xp);
      if (mk) {
        int hb = 63 - __builtin_clzll(mk);
        lm = fminf(lm, (lane > hb) ? v : __builtin_inff());
        done = true;
      } else {
        lm = fminf(lm, (idx >= 0) ? v : __builtin_inff());
        done = (p - 64*(s+1) <= 0);
      }
    }
    float lmin = wave_min(lm);
    float rm = xp; done = false;
    for (int s = 0; !done; ++s) {
      int idx = p + 1 + 64*s + lane;
      float v = (idx < LSEQ) ? xsp[idx] : -__builtin_inff();
      unsigned long long mk = __ballot(v > xp);
      if (mk) {
        int lb_ = __builtin_ctzll(mk);
        rm = fminf(rm, (lane < lb_) ? v : __builtin_inff());
        done = true;
      } else {
        rm = fminf(rm, (idx < LSEQ) ? v : __builtin_inff());
        done = (p + 64 + 64*s >= LSEQ-1);
      }
    }
    float rmin = wave_min(rm);
    if (lane == 0 && (xp - fmaxf(lmin, rmin)) >= pthr) peaks[p] = 1;
  }
  __syncthreads();

  const float inv = 1.f / (sd + 1e-5f);
  for (int i = tid; i < LSEQ; i += 256) {
    float w_ = 1.f + 0.1f * (float)peaks[i];
    h0[(size_t)b*LSEQ + i] = (w_ * (xsp[i] - m)) * inv;
  }
}

// ---------- prep: zero stats+feat, coalesced per-co weight transpose fp32->bf16 [t][co][ci] ----------
__global__ __launch_bounds__(256)
void prep_all(const float* __restrict__ w1, const float* __restrict__ w2,
              const float* __restrict__ w3, const float* __restrict__ w4,
              const float* __restrict__ w5,
              __hip_bfloat16* __restrict__ o1, __hip_bfloat16* __restrict__ o2,
              __hip_bfloat16* __restrict__ o3, __hip_bfloat16* __restrict__ o4,
              __hip_bfloat16* __restrict__ o5,
              float* __restrict__ zbuf)
{
  __shared__ float tile[6400];
  int b = blockIdx.x, tid = threadIdx.x;
  if (b < 44) { int i = b*256 + tid; if (i < 11264) zbuf[i] = 0.f; return; }
  b -= 44;
  const float* w; __hip_bfloat16* o; int COUT, CIN, K, co;
  if      (b < 64)  { w=w1; o=o1; COUT=64;  CIN=64;  K=5;  co=b;     }
  else if (b < 192) { w=w2; o=o2; COUT=128; CIN=64;  K=15; co=b-64;  }
  else if (b < 320) { w=w3; o=o3; COUT=128; CIN=128; K=15; co=b-192; }
  else if (b < 576) { w=w4; o=o4; COUT=256; CIN=128; K=25; co=b-320; }
  else              { w=w5; o=o5; COUT=256; CIN=256; K=25; co=b-576; }
  const int n = CIN * K;
  const float* src = w + (size_t)co * n;
  for (int i = tid; i < n; i += 256) tile[i] = src[i];          // tile[ci*K + t]
  __syncthreads();
  for (int i = tid; i < n; i += 256) {
    int t = i / CIN, ci = i - t*CIN;
    o[((size_t)t*COUT + co)*CIN + ci] = __float2bfloat16(tile[ci*K + t]);
  }
}

// ---------- conv0: 1->64, K=5, scalar ----------
__global__ __launch_bounds__(256)
void conv0_kernel(const float* __restrict__ h0, const float* __restrict__ w,
                  const float* __restrict__ cb, __hip_bfloat16* __restrict__ out,
                  float* __restrict__ S1, float* __restrict__ S2)
{
  __shared__ float sw[320], sb[64];
  __shared__ float red[2][4][64];
  const int tid = threadIdx.x, lane = tid & 63, wv = tid >> 6;
  for (int i = tid; i < 320; i += 256) sw[i] = w[i];
  if (tid < 64) sb[tid] = cb[tid];
  __syncthreads();
  const int b = blockIdx.y;
  const float* xr = h0 + (size_t)b * LSEQ;
  float s1 = 0.f, s2 = 0.f;
  #pragma unroll
  for (int q = 0; q < 4; ++q) {
    int pos = blockIdx.x*16 + q*4 + wv;
    float xv[5];
    #pragma unroll
    for (int k = 0; k < 5; ++k) {
      int gp = pos - 2 + k;
      xv[k] = (gp >= 0 && gp < LSEQ) ? xr[gp] : 0.f;
    }
    float y = sb[lane];
    #pragma unroll
    for (int k = 0; k < 5; ++k) y = fmaf(sw[lane*5+k], xv[k], y);
    out[((size_t)b*LSEQ + pos)*64 + lane] = __float2bfloat16(y);
    s1 += y; s2 += y*y;
  }
  red[0][wv][lane] = s1; red[1][wv][lane] = s2;
  __syncthreads();
  if (wv == 0) {
    s1 = red[0][0][lane]+red[0][1][lane]+red[0][2][lane]+red[0][3][lane];
    s2 = red[1][0][lane]+red[1][1][lane]+red[1][2][lane]+red[1][3][lane];
    atomicAdd(&S1[lane], s1);
    atomicAdd(&S2[lane], s2);
  }
}

// ---------- MFMA implicit-GEMM conv, 16x16x32, tap-interleaved async DMA ----------
// (converged round-13/15/17 configuration; body in a device fn so each layer
//  gets a DISTINCT kernel name in the profile — zero codegen change intended)
template<int CIN, int COUT, int K, int BM, int NPOS>
__device__ __forceinline__
void conv_impl(const __hip_bfloat16* __restrict__ in,
               const __hip_bfloat16* __restrict__ wb,
               const float* __restrict__ cb,
               const float* __restrict__ S1p, const float* __restrict__ S2p,
               const float* __restrict__ g, const float* __restrict__ be,
               __hip_bfloat16* __restrict__ out,
               float* __restrict__ S1, float* __restrict__ S2)
{
  constexpr int PAD = K/2, XR = NPOS + K - 1;
  constexpr int WM_T = BM/2, MF = WM_T/16;
  constexpr int WN_T = NPOS/2, NF = WN_T/16;
  constexpr int NIDX = XR*8;
  constexpr int NCH = (NIDX + 255)/256;

  __shared__ float s_sc[CIN], s_sh[CIN];
  __shared__ alignas(16) char XsB[XR*128];       // swizzled [pos][64ci]
  __shared__ alignas(16) char Raw[NCH*4096];     // linear DMA landing zone

  const int tid = threadIdx.x;
  const int lane = tid & 63;
  const int wid = tid >> 6;
  const int wm = wid >> 1, wn = wid & 1;
  const int b = blockIdx.z;
  const int p0 = blockIdx.x * NPOS;
  const int co0 = blockIdx.y * BM;
  const int colp = lane & 15, rgrp = lane >> 4;

  const size_t brow = (size_t)b * LSEQ;

  auto dma_one = [&](int cic, int q){
    int idx = tid + q*256;
    int r = idx >> 3, ch = idx & 7;
    int gp = p0 - PAD + r;
    int gpc = gp < 0 ? 0 : (gp > LSEQ-1 ? LSEQ-1 : gp);
    gl_lds16(in + (brow + gpc)*CIN + cic + ch*8, Raw + idx*16);
  };
  auto issue_dma = [&](int cic){
    #pragma unroll
    for (int q = 0; q < NCH; ++q) dma_one(cic, q);
  };

  issue_dma(0);     // first chunk's DMA flies under the BN-finalize preamble

  const float invN = 1.f / 65536.f;
  for (int i = tid; i < CIN; i += 256) {
    float mm = S1p[i] * invN;
    float var = fmaxf(S2p[i] * invN - mm*mm, 0.f);
    float sc = g[i] / sqrtf(var + 1e-5f);
    s_sc[i] = sc;
    s_sh[i] = be[i] - mm * sc;
  }

  float4v acc[MF][NF];
  #pragma unroll
  for (int mf = 0; mf < MF; ++mf) {
    #pragma unroll
    for (int nf = 0; nf < NF; ++nf) acc[mf][nf] = (float4v){0.f,0.f,0.f,0.f};
  }

  const __hip_bfloat16* wlane = wb + ((size_t)(co0 + wm*WM_T + colp))*CIN + rgrp*8;

  auto transform = [&](int cic){
    #pragma unroll
    for (int q = 0; q < NCH; ++q) {
      int idx = tid + q*256;
      if (idx < NIDX) {
        int r = idx >> 3, ch = idx & 7;
        int gp = p0 - PAD + r;
        uint4 v = make_uint4(0u,0u,0u,0u);
        if (gp >= 0 && gp < LSEQ) {
          v = *(const uint4*)(Raw + idx*16);
          v = bn_pack(v, s_sc, s_sh, cic + ch*8);
        }
        *(uint4*)(XsB + r*128 + ((ch*16) ^ ((r&7)<<4))) = v;
      }
    }
  };

  for (int cic = 0; cic < CIN; cic += 64) {
    __syncthreads();            // prev compute done with XsB; DMA long complete
    transform(cic);
    __syncthreads();            // XsB visible; Raw free for next chunk's DMA
    const bool nxtc = (cic + 64 < CIN);
    const int nc = cic + 64;

    const __hip_bfloat16* wch = wlane + cic;

    auto wfrag = [&](short8v (&dst)[2][MF], int tap) {
      #pragma unroll
      for (int kk = 0; kk < 2; ++kk) {
        #pragma unroll
        for (int mf = 0; mf < MF; ++mf) {
          dst[kk][mf] = *(const short8v*)(wch + ((size_t)tap*COUT + mf*16)*CIN + kk*32);
        }
      }
    };
    auto do_tap = [&](short8v (&cur)[2][MF], short8v (&nxt)[2][MF], int t) {
      if (t+1 < K) wfrag(nxt, t+1);       // prefetch next tap's weights
      if (nxtc && t < NCH) dma_one(nc, t); // interleave next-chunk DMA, 1 batch/tap
      __builtin_amdgcn_s_setprio(1);
      #pragma unroll
      for (int kk = 0; kk < 2; ++kk) {
        short8v bfr[NF];
        #pragma unroll
        for (int nf = 0; nf < NF; ++nf) {
          int rr = wn*WN_T + nf*16 + colp + t;
          bfr[nf] = *(const short8v*)(XsB + rr*128 + ((kk*64 + rgrp*16) ^ ((rr&7)<<4)));
        }
        #pragma unroll
        for (int mf = 0; mf < MF; ++mf) {
          #pragma unroll
          for (int nf = 0; nf < NF; ++nf) {
            acc[mf][nf] = __builtin_amdgcn_mfma_f32_16x16x32_bf16(cur[kk][mf], bfr[nf], acc[mf][nf], 0, 0, 0);
          }
        }
      }
      __builtin_amdgcn_s_setprio(0);
    };
    short8v afE[2][MF], afO[2][MF];
    wfrag(afE, 0);
    for (int t = 0; t < K; t += 2) {
      do_tap(afE, afO, t);
      if (t+1 < K) do_tap(afO, afE, t+1);
    }
    if (nxtc) {                            // leftover batches if K < NCH
      for (int q = K; q < NCH; ++q) dma_one(nc, q);
    }
  }

  // staged coalesced epilogue (co-half0 -> XsB, co-half1 -> Raw)
  __syncthreads();
  #pragma unroll
  for (int mf = 0; mf < MF; ++mf) {
    int co_rel = wm*WM_T + mf*16 + rgrp*4;
    int co_b = co0 + co_rel;
    float b0 = cb[co_b+0], b1 = cb[co_b+1], b2 = cb[co_b+2], b3 = cb[co_b+3];
    float s1v[4] = {0,0,0,0}, s2v[4] = {0,0,0,0};
    char* sbase = (co_rel*2 < 128) ? XsB : Raw;
    int cb2 = (co_rel*2) & 127;
    #pragma unroll
    for (int nf = 0; nf < NF; ++nf) {
      int pl = wn*WN_T + nf*16 + colp;
      float y0 = acc[mf][nf][0] + b0;
      float y1 = acc[mf][nf][1] + b1;
      float y2 = acc[mf][nf][2] + b2;
      float y3 = acc[mf][nf][3] + b3;
      ushort4 pk = make_ushort4(f2b(y0), f2b(y1), f2b(y2), f2b(y3));
      *(ushort4*)(sbase + pl*128 + (cb2 ^ ((pl&7)<<4))) = pk;
      s1v[0]+=y0; s1v[1]+=y1; s1v[2]+=y2; s1v[3]+=y3;
      s2v[0]+=y0*y0; s2v[1]+=y1*y1; s2v[2]+=y2*y2; s2v[3]+=y3*y3;
    }
    #pragma unroll
    for (int off = 1; off < 16; off <<= 1) {
      #pragma unroll
      for (int r = 0; r < 4; ++r) {
        s1v[r] += __shfl_xor(s1v[r], off, 64);
        s2v[r] += __shfl_xor(s2v[r], off, 64);
      }
    }
    if (colp == 0) {
      #pragma unroll
      for (int r = 0; r < 4; ++r) {
        atomicAdd(&S1[co_b+r], s1v[r]);
        atomicAdd(&S2[co_b+r], s2v[r]);
      }
    }
  }
  __syncthreads();
  constexpr int OW = BM/8;     // uint4 chunks per output row
  for (int idx = tid; idx < NPOS*OW; idx += 256) {
    int r = idx / OW, c16 = idx - r*OW;
    const char* sbase = (c16*16 < 128) ? XsB : Raw;
    int cbb = (c16*16) & 127;
    uint4 v = *(const uint4*)(sbase + r*128 + (cbb ^ ((r&7)<<4)));
    *(uint4*)(out + (brow + p0 + r)*COUT + co0 + c16*8) = v;
  }
}

#define CONV_ARGS const __hip_bfloat16* in, const __hip_bfloat16* wb, const float* cb, \
                  const float* S1p, const float* S2p, const float* g, const float* be, \
                  __hip_bfloat16* out, float* S1, float* S2

__global__ __launch_bounds__(256, 2) void conv_l1(CONV_ARGS){ conv_impl<64,64,5,64,256>(in,wb,cb,S1p,S2p,g,be,out,S1,S2); }
__global__ __launch_bounds__(256, 2) void conv_l2(CONV_ARGS){ conv_impl<64,128,15,128,256>(in,wb,cb,S1p,S2p,g,be,out,S1,S2); }
__global__ __launch_bounds__(256, 2) void conv_l3(CONV_ARGS){ conv_impl<128,128,15,128,256>(in,wb,cb,S1p,S2p,g,be,out,S1,S2); }
__global__ __launch_bounds__(256, 2) void conv_l4(CONV_ARGS){ conv_impl<128,256,25,128,256>(in,wb,cb,S1p,S2p,g,be,out,S1,S2); }
__global__ __launch_bounds__(256, 2) void conv_l5(CONV_ARGS){ conv_impl<256,256,25,128,256>(in,wb,cb,S1p,S2p,g,be,out,S1,S2); }

// ---------- feat: sum over L of relu(bn(a5)) with in-kernel BN finalize ----------
__global__ __launch_bounds__(256)
void feat_accum(const __hip_bfloat16* __restrict__ a,
                const float* __restrict__ S1, const float* __restrict__ S2,
                const float* __restrict__ g, const float* __restrict__ be,
                float* __restrict__ feat)
{
  const int b = blockIdx.y, chunk = blockIdx.x, c = threadIdx.x;
  const float invN = 1.f / 65536.f;
  float mm = S1[c] * invN;
  float var = fmaxf(S2[c] * invN - mm*mm, 0.f);
  float sc = g[c] / sqrtf(var + 1e-5f);
  float sh = be[c] - mm * sc;
  float s = 0.f;
  const __hip_bfloat16* p = a + ((size_t)b*LSEQ + chunk*256)*256 + c;
  #pragma unroll 4
  for (int i = 0; i < 256; ++i)
    s += fmaxf(fmaf(__bfloat162float(p[(size_t)i*256]), sc, sh), 0.f);
  atomicAdd(&feat[b*256 + c], s);
}

// ---------- head: two 32x64x256 GEMVs ----------
__global__ __launch_bounds__(256)
void head_kernel(const float* __restrict__ feat, const float* __restrict__ wm,
                 const float* __restrict__ bm, const float* __restrict__ wv,
                 const float* __restrict__ bv, float* __restrict__ out)
{
  int idx = blockIdx.x*256 + threadIdx.x;
  int sel = idx >> 11, rem = idx & 2047, b = rem >> 6, j = rem & 63;
  const float* W = sel ? wv : wm;
  const float* bias = sel ? bv : bm;
  const float4* f = (const float4*)(feat + b*256);
  const float4* wr = (const float4*)(W + j*256);
  float acc = 0.f;
  #pragma unroll 4
  for (int c = 0; c < 64; ++c) {
    float4 a4 = f[c], w4 = wr[c];
    acc += a4.x*w4.x + a4.y*w4.y + a4.z*w4.z + a4.w*w4.w;
  }
  out[idx] = acc * (1.f/(float)LSEQ) + bias[j];
}

extern "C" void kernel_launch(void* const* d_in, const int* in_sizes, int n_in,
                              void* d_out, int out_size, void* d_ws, size_t ws_size,
                              hipStream_t stream)
{
  (void)in_sizes; (void)n_in; (void)out_size; (void)ws_size;
  const float* x = (const float*)d_in[0];
  const float *cw[6], *cbp[6], *bg[6], *bb[6];
  for (int i = 0; i < 6; i++){
    cw[i]=(const float*)d_in[1+4*i]; cbp[i]=(const float*)d_in[2+4*i];
    bg[i]=(const float*)d_in[3+4*i]; bb[i]=(const float*)d_in[4+4*i];
  }
  const float* wmh=(const float*)d_in[25]; const float* bmh=(const float*)d_in[26];
  const float* wvh=(const float*)d_in[27]; const float* bvh=(const float*)d_in[28];

  char* ws = (char*)d_ws;
  size_t off = 0;
  float* h0 = (float*)(ws+off);            off += (size_t)NB*LSEQ*4;
  __hip_bfloat16* bufA = (__hip_bfloat16*)(ws+off); off += (size_t)NB*LSEQ*256*2;
  __hip_bfloat16* bufB = (__hip_bfloat16*)(ws+off); off += (size_t)NB*LSEQ*256*2;
  __hip_bfloat16* wb1 = (__hip_bfloat16*)(ws+off); off += (size_t)5*64*64*2;
  __hip_bfloat16* wb2 = (__hip_bfloat16*)(ws+off); off += (size_t)15*128*64*2;
  __hip_bfloat16* wb3 = (__hip_bfloat16*)(ws+off); off += (size_t)15*128*128*2;
  __hip_bfloat16* wb4 = (__hip_bfloat16*)(ws+off); off += (size_t)25*256*128*2;
  __hip_bfloat16* wb5 = (__hip_bfloat16*)(ws+off); off += (size_t)25*256*256*2;
  float* stats = (float*)(ws+off);         off += 3072*4;
  float* feat  = (float*)(ws+off);         off += (size_t)NB*256*4;   // contiguous with stats
  float* S1 = stats; float* S2 = stats + 1536;

  // blocks 0..43 zero stats+feat; blocks 44..875 transpose/convert weights (coalesced)
  prep_all<<<876, 256, 0, stream>>>(cw[1], cw[2], cw[3], cw[4], cw[5],
                                    wb1, wb2, wb3, wb4, wb5, stats);

  row_prep<<<NB, 256, 0, stream>>>(x, h0);

  conv0_kernel<<<dim3(128, NB), 256, 0, stream>>>(h0, cw[0], cbp[0], bufA, S1+0, S2+0);

  conv_l1<<<dim3(8,1,NB),256,0,stream>>>(
      bufA, wb1, cbp[1], S1+0, S2+0, bg[0], bb[0], bufB, S1+256, S2+256);

  conv_l2<<<dim3(8,1,NB),256,0,stream>>>(
      bufB, wb2, cbp[2], S1+256, S2+256, bg[1], bb[1], bufA, S1+512, S2+512);

  conv_l3<<<dim3(8,1,NB),256,0,stream>>>(
      bufA, wb3, cbp[3], S1+512, S2+512, bg[2], bb[2], bufB, S1+768, S2+768);

  conv_l4<<<dim3(8,2,NB),256,0,stream>>>(
      bufB, wb4, cbp[4], S1+768, S2+768, bg[3], bb[3], bufA, S1+1024, S2+1024);

  conv_l5<<<dim3(8,2,NB),256,0,stream>>>(
      bufA, wb5, cbp[5], S1+1024, S2+1024, bg[4], bb[4], bufB, S1+1280, S2+1280);

  feat_accum<<<dim3(8, NB), 256, 0, stream>>>(bufB, S1+1280, S2+1280, bg[5], bb[5], feat);
  head_kernel<<<16, 256, 0, stream>>>(feat, wmh, bmh, wvh, bvh, (float*)d_out);
}

// Round 19
// 808.121 us; speedup vs baseline: 1.0277x; 1.0277x over previous
//
#include <hip/hip_runtime.h>
#include <hip/hip_bf16.h>

#define LSEQ 2048
#define NB 32

typedef __attribute__((ext_vector_type(8))) short short8v;
typedef __attribute__((ext_vector_type(4))) float float4v;

// ---------- dtype helpers ----------
__device__ __forceinline__ unsigned short f2b(float f){
  __hip_bfloat16 h = __float2bfloat16(f);
  return *reinterpret_cast<unsigned short*>(&h);
}
__device__ __forceinline__ float b2f_bits(unsigned short u){
  unsigned int x = ((unsigned int)u) << 16; return __uint_as_float(x);
}

__device__ __forceinline__ float wave_min(float v){
  #pragma unroll
  for (int off = 32; off; off >>= 1) v = fminf(v, __shfl_xor(v, off, 64));
  return v;
}

// apply BN(scale,shift)+relu to 8 bf16 packed in uint4, repack to bf16
__device__ __forceinline__ uint4 bn_pack(uint4 g, const float* sc, const float* sh, int cbase){
  union { uint4 u; unsigned short us[8]; } in_, out_;
  in_.u = g;
  #pragma unroll
  for (int j = 0; j < 8; ++j){
    float v = b2f_bits(in_.us[j]);
    v = fmaxf(fmaf(v, sc[cbase+j], sh[cbase+j]), 0.f);
    out_.us[j] = f2b(v);
  }
  return out_.u;
}

// async 16B global -> LDS
__device__ __forceinline__ void gl_lds16(const void* g, void* l){
  __builtin_amdgcn_global_load_lds(
      (const __attribute__((address_space(1))) void*)g,
      (__attribute__((address_space(3))) void*)l, 16, 0, 0);
}

// ---------- row preprocessing + conv0 fused ----------
// stats + find_peaks + normalize (in LDS), then conv0 (1->64, K=5) straight
// from the normalized LDS row -> bufA [b][pos][64] bf16 + conv0 stats.
__global__ __launch_bounds__(256)
void row_prep_c0(const float* __restrict__ x,
                 const float* __restrict__ w0, const float* __restrict__ cb0,
                 __hip_bfloat16* __restrict__ out,
                 float* __restrict__ S1, float* __restrict__ S2)
{
  const int b = blockIdx.x, tid = threadIdx.x;
  const int lane = tid & 63, wid = tid >> 6;
  __shared__ float xs_raw[LSEQ + 18];
  __shared__ unsigned char st_raw[LSEQ + 18];
  __shared__ unsigned char peaks[LSEQ];
  __shared__ short s_cand[1024];
  __shared__ short s_kept[256];
  __shared__ int s_flag, s_cnt, s_kcnt;
  __shared__ float s_redA[4], s_redB[4];
  __shared__ float s_mx, s_mean, s_std;
  __shared__ float sw[320], sb[64];
  __shared__ float redA[4][64], redB[4][64];
  float* xsp = xs_raw + 9;
  unsigned char* stp = st_raw + 9;

  const float* xr = x + (size_t)b * LSEQ;
  for (int i = tid; i < LSEQ; i += 256) xsp[i] = xr[i];
  for (int i = tid; i < 18; i += 256) {
    xs_raw[(i < 9) ? i : (LSEQ + i)] = -__builtin_inff();
    st_raw[(i < 9) ? i : (LSEQ + i)] = 2;
  }
  for (int i = tid; i < 320; i += 256) sw[i] = w0[i];
  if (tid < 64) sb[tid] = cb0[tid];
  if (tid == 0) { s_cnt = 0; s_kcnt = 0; }
  __syncthreads();

  float vmax = -__builtin_inff(), vsum = 0.f;
  for (int i = tid; i < LSEQ; i += 256) { float v = xsp[i]; vmax = fmaxf(vmax, v); vsum += v; }
  #pragma unroll
  for (int off = 32; off; off >>= 1){
    vmax = fmaxf(vmax, __shfl_xor(vmax, off, 64));
    vsum += __shfl_xor(vsum, off, 64);
  }
  if (lane == 0){ s_redA[wid] = vmax; s_redB[wid] = vsum; }
  __syncthreads();
  if (tid == 0){
    s_mx   = fmaxf(fmaxf(s_redA[0], s_redA[1]), fmaxf(s_redA[2], s_redA[3]));
    s_mean = (s_redB[0]+s_redB[1]+s_redB[2]+s_redB[3]) * (1.f/(float)LSEQ);
  }
  __syncthreads();
  const float m = s_mean, mx = s_mx;

  float vss = 0.f;
  for (int i = tid; i < LSEQ; i += 256){ float d = xsp[i]-m; vss += d*d; }
  #pragma unroll
  for (int off = 32; off; off >>= 1) vss += __shfl_xor(vss, off, 64);
  if (lane == 0) s_redA[wid] = vss;
  __syncthreads();
  if (tid == 0) s_std = sqrtf((s_redA[0]+s_redA[1]+s_redA[2]+s_redA[3]) / (float)(LSEQ-1));
  __syncthreads();
  const float sd = s_std;

  const float hthr = 0.1f * mx;
  for (int i = tid; i < LSEQ; i += 256) {
    unsigned char c = 2;
    if (i >= 1 && i <= LSEQ-2) {
      float v = xsp[i];
      if ((v > xsp[i-1]) && (v > xsp[i+1]) && (v >= hthr)) {
        c = 0;
        int s = atomicAdd(&s_cnt, 1);
        if (s < 1024) s_cand[s] = (short)i;
      }
    }
    stp[i] = c; peaks[i] = 0;
  }
  __syncthreads();
  const int cnt = (s_cnt < 1024) ? s_cnt : 1024;

  for (int round = 0; round < 1024; ++round) {
    if (tid == 0) s_flag = 0;
    __syncthreads();
    int und = 0;
    for (int q = tid; q < cnt; q += 256) {
      int i = s_cand[q];
      if (stp[i] == 0) {
        float xi = xsp[i];
        bool anyK = false, allD = true;
        #pragma unroll
        for (int o = -9; o <= 9; ++o) {
          if (o == 0) continue;
          unsigned char s = stp[i+o];
          float xj = xsp[i+o];
          bool hi = (xj > xi) || (xj == xi && o < 0);
          anyK = anyK || (hi && s == 1);
          allD = allD && ((!hi) || s == 2);
        }
        unsigned char ns = anyK ? 2 : (allD ? 1 : 0);
        if (ns) stp[i] = ns; else und = 1;
      }
    }
    if (und) s_flag = 1;
    __syncthreads();
    if (!s_flag) break;
  }

  for (int q = tid; q < cnt; q += 256) {
    int i = s_cand[q];
    if (stp[i] == 1) { int s = atomicAdd(&s_kcnt, 1); s_kept[s] = (short)i; }
  }
  __syncthreads();
  const int M = s_kcnt;
  const float pthr = 0.05f * mx;

  for (int c = wid; c < M; c += 4) {
    int p = s_kept[c]; float xp = xsp[p];
    float lm = xp; bool done = false;
    for (int s = 0; !done; ++s) {
      int idx = p - 64*(s+1) + lane;
      float v = (idx >= 0) ? xsp[idx] : -__builtin_inff();
      unsigned long long mk = __ballot(v > xp);
      if (mk) {
        int hb = 63 - __builtin_clzll(mk);
        lm = fminf(lm, (lane > hb) ? v : __builtin_inff());
        done = true;
      } else {
        lm = fminf(lm, (idx >= 0) ? v : __builtin_inff());
        done = (p - 64*(s+1) <= 0);
      }
    }
    float lmin = wave_min(lm);
    float rm = xp; done = false;
    for (int s = 0; !done; ++s) {
      int idx = p + 1 + 64*s + lane;
      float v = (idx < LSEQ) ? xsp[idx] : -__builtin_inff();
      unsigned long long mk = __ballot(v > xp);
      if (mk) {
        int lb_ = __builtin_ctzll(mk);
        rm = fminf(rm, (lane < lb_) ? v : __builtin_inff());
        done = true;
      } else {
        rm = fminf(rm, (idx < LSEQ) ? v : __builtin_inff());
        done = (p + 64 + 64*s >= LSEQ-1);
      }
    }
    float rmin = wave_min(rm);
    if (lane == 0 && (xp - fmaxf(lmin, rmin)) >= pthr) peaks[p] = 1;
  }
  __syncthreads();

  // normalize in place: xsp becomes h0 (peaks/prominence all done)
  const float inv = 1.f / (sd + 1e-5f);
  for (int i = tid; i < LSEQ; i += 256) {
    float w_ = 1.f + 0.1f * (float)peaks[i];
    xsp[i] = (w_ * (xsp[i] - m)) * inv;
  }
  __syncthreads();

  // conv0 from LDS row: thread owns co = tid&63, positions pgrp,pgrp+4,...
  const int co = tid & 63, pgrp = tid >> 6;
  float wk0 = sw[co*5+0], wk1 = sw[co*5+1], wk2 = sw[co*5+2],
        wk3 = sw[co*5+3], wk4 = sw[co*5+4];
  const float bias = sb[co];
  float s1 = 0.f, s2 = 0.f;
  __hip_bfloat16* orow = out + (size_t)b * LSEQ * 64 + co;
  for (int pos = pgrp; pos < LSEQ; pos += 4) {
    float x0 = (pos-2 >= 0)   ? xsp[pos-2] : 0.f;
    float x1 = (pos-1 >= 0)   ? xsp[pos-1] : 0.f;
    float x2 = xsp[pos];
    float x3 = (pos+1 < LSEQ) ? xsp[pos+1] : 0.f;
    float x4 = (pos+2 < LSEQ) ? xsp[pos+2] : 0.f;
    float y = bias;
    y = fmaf(wk0, x0, y);
    y = fmaf(wk1, x1, y);
    y = fmaf(wk2, x2, y);
    y = fmaf(wk3, x3, y);
    y = fmaf(wk4, x4, y);
    orow[(size_t)pos*64] = __float2bfloat16(y);
    s1 += y; s2 += y*y;
  }
  redA[pgrp][co] = s1; redB[pgrp][co] = s2;
  __syncthreads();
  if (tid < 64) {
    float a = redA[0][tid]+redA[1][tid]+redA[2][tid]+redA[3][tid];
    float bb = redB[0][tid]+redB[1][tid]+redB[2][tid]+redB[3][tid];
    atomicAdd(&S1[tid], a);
    atomicAdd(&S2[tid], bb);
  }
}

// ---------- prep: zero stats+feat, coalesced per-co weight transpose fp32->bf16 [t][co][ci] ----------
__global__ __launch_bounds__(256)
void prep_all(const float* __restrict__ w1, const float* __restrict__ w2,
              const float* __restrict__ w3, const float* __restrict__ w4,
              const float* __restrict__ w5,
              __hip_bfloat16* __restrict__ o1, __hip_bfloat16* __restrict__ o2,
              __hip_bfloat16* __restrict__ o3, __hip_bfloat16* __restrict__ o4,
              __hip_bfloat16* __restrict__ o5,
              float* __restrict__ zbuf)
{
  __shared__ float tile[6400];
  int b = blockIdx.x, tid = threadIdx.x;
  if (b < 44) { int i = b*256 + tid; if (i < 11264) zbuf[i] = 0.f; return; }
  b -= 44;
  const float* w; __hip_bfloat16* o; int COUT, CIN, K, co;
  if      (b < 64)  { w=w1; o=o1; COUT=64;  CIN=64;  K=5;  co=b;     }
  else if (b < 192) { w=w2; o=o2; COUT=128; CIN=64;  K=15; co=b-64;  }
  else if (b < 320) { w=w3; o=o3; COUT=128; CIN=128; K=15; co=b-192; }
  else if (b < 576) { w=w4; o=o4; COUT=256; CIN=128; K=25; co=b-320; }
  else              { w=w5; o=o5; COUT=256; CIN=256; K=25; co=b-576; }
  const int n = CIN * K;
  const float* src = w + (size_t)co * n;
  for (int i = tid; i < n; i += 256) tile[i] = src[i];          // tile[ci*K + t]
  __syncthreads();
  for (int i = tid; i < n; i += 256) {
    int t = i / CIN, ci = i - t*CIN;
    o[((size_t)t*COUT + co)*CIN + ci] = __float2bfloat16(tile[ci*K + t]);
  }
}

// ---------- MFMA implicit-GEMM conv, 16x16x32, tap-interleaved async DMA ----------
// (converged configuration; body in a device fn, per-layer named wrappers)
template<int CIN, int COUT, int K, int BM, int NPOS>
__device__ __forceinline__
void conv_impl(const __hip_bfloat16* __restrict__ in,
               const __hip_bfloat16* __restrict__ wb,
               const float* __restrict__ cb,
               const float* __restrict__ S1p, const float* __restrict__ S2p,
               const float* __restrict__ g, const float* __restrict__ be,
               __hip_bfloat16* __restrict__ out,
               float* __restrict__ S1, float* __restrict__ S2)
{
  constexpr int PAD = K/2, XR = NPOS + K - 1;
  constexpr int WM_T = BM/2, MF = WM_T/16;
  constexpr int WN_T = NPOS/2, NF = WN_T/16;
  constexpr int NIDX = XR*8;
  constexpr int NCH = (NIDX + 255)/256;

  __shared__ float s_sc[CIN], s_sh[CIN];
  __shared__ alignas(16) char XsB[XR*128];       // swizzled [pos][64ci]
  __shared__ alignas(16) char Raw[NCH*4096];     // linear DMA landing zone

  const int tid = threadIdx.x;
  const int lane = tid & 63;
  const int wid = tid >> 6;
  const int wm = wid >> 1, wn = wid & 1;
  const int b = blockIdx.z;
  const int p0 = blockIdx.x * NPOS;
  const int co0 = blockIdx.y * BM;
  const int colp = lane & 15, rgrp = lane >> 4;

  const size_t brow = (size_t)b * LSEQ;

  auto dma_one = [&](int cic, int q){
    int idx = tid + q*256;
    int r = idx >> 3, ch = idx & 7;
    int gp = p0 - PAD + r;
    int gpc = gp < 0 ? 0 : (gp > LSEQ-1 ? LSEQ-1 : gp);
    gl_lds16(in + (brow + gpc)*CIN + cic + ch*8, Raw + idx*16);
  };
  auto issue_dma = [&](int cic){
    #pragma unroll
    for (int q = 0; q < NCH; ++q) dma_one(cic, q);
  };

  issue_dma(0);     // first chunk's DMA flies under the BN-finalize preamble

  const float invN = 1.f / 65536.f;
  for (int i = tid; i < CIN; i += 256) {
    float mm = S1p[i] * invN;
    float var = fmaxf(S2p[i] * invN - mm*mm, 0.f);
    float sc = g[i] / sqrtf(var + 1e-5f);
    s_sc[i] = sc;
    s_sh[i] = be[i] - mm * sc;
  }

  float4v acc[MF][NF];
  #pragma unroll
  for (int mf = 0; mf < MF; ++mf) {
    #pragma unroll
    for (int nf = 0; nf < NF; ++nf) acc[mf][nf] = (float4v){0.f,0.f,0.f,0.f};
  }

  const __hip_bfloat16* wlane = wb + ((size_t)(co0 + wm*WM_T + colp))*CIN + rgrp*8;

  auto transform = [&](int cic){
    #pragma unroll
    for (int q = 0; q < NCH; ++q) {
      int idx = tid + q*256;
      if (idx < NIDX) {
        int r = idx >> 3, ch = idx & 7;
        int gp = p0 - PAD + r;
        uint4 v = make_uint4(0u,0u,0u,0u);
        if (gp >= 0 && gp < LSEQ) {
          v = *(const uint4*)(Raw + idx*16);
          v = bn_pack(v, s_sc, s_sh, cic + ch*8);
        }
        *(uint4*)(XsB + r*128 + ((ch*16) ^ ((r&7)<<4))) = v;
      }
    }
  };

  for (int cic = 0; cic < CIN; cic += 64) {
    __syncthreads();            // prev compute done with XsB; DMA long complete
    transform(cic);
    __syncthreads();            // XsB visible; Raw free for next chunk's DMA
    const bool nxtc = (cic + 64 < CIN);
    const int nc = cic + 64;

    const __hip_bfloat16* wch = wlane + cic;

    auto wfrag = [&](short8v (&dst)[2][MF], int tap) {
      #pragma unroll
      for (int kk = 0; kk < 2; ++kk) {
        #pragma unroll
        for (int mf = 0; mf < MF; ++mf) {
          dst[kk][mf] = *(const short8v*)(wch + ((size_t)tap*COUT + mf*16)*CIN + kk*32);
        }
      }
    };
    auto do_tap = [&](short8v (&cur)[2][MF], short8v (&nxt)[2][MF], int t) {
      if (t+1 < K) wfrag(nxt, t+1);       // prefetch next tap's weights
      if (nxtc && t < NCH) dma_one(nc, t); // interleave next-chunk DMA, 1 batch/tap
      __builtin_amdgcn_s_setprio(1);
      #pragma unroll
      for (int kk = 0; kk < 2; ++kk) {
        short8v bfr[NF];
        #pragma unroll
        for (int nf = 0; nf < NF; ++nf) {
          int rr = wn*WN_T + nf*16 + colp + t;
          bfr[nf] = *(const short8v*)(XsB + rr*128 + ((kk*64 + rgrp*16) ^ ((rr&7)<<4)));
        }
        #pragma unroll
        for (int mf = 0; mf < MF; ++mf) {
          #pragma unroll
          for (int nf = 0; nf < NF; ++nf) {
            acc[mf][nf] = __builtin_amdgcn_mfma_f32_16x16x32_bf16(cur[kk][mf], bfr[nf], acc[mf][nf], 0, 0, 0);
          }
        }
      }
      __builtin_amdgcn_s_setprio(0);
    };
    short8v afE[2][MF], afO[2][MF];
    wfrag(afE, 0);
    for (int t = 0; t < K; t += 2) {
      do_tap(afE, afO, t);
      if (t+1 < K) do_tap(afO, afE, t+1);
    }
    if (nxtc) {                            // leftover batches if K < NCH
      for (int q = K; q < NCH; ++q) dma_one(nc, q);
    }
  }

  // staged coalesced epilogue (co-half0 -> XsB, co-half1 -> Raw)
  __syncthreads();
  #pragma unroll
  for (int mf = 0; mf < MF; ++mf) {
    int co_rel = wm*WM_T + mf*16 + rgrp*4;
    int co_b = co0 + co_rel;
    float b0 = cb[co_b+0], b1 = cb[co_b+1], b2 = cb[co_b+2], b3 = cb[co_b+3];
    float s1v[4] = {0,0,0,0}, s2v[4] = {0,0,0,0};
    char* sbase = (co_rel*2 < 128) ? XsB : Raw;
    int cb2 = (co_rel*2) & 127;
    #pragma unroll
    for (int nf = 0; nf < NF; ++nf) {
      int pl = wn*WN_T + nf*16 + colp;
      float y0 = acc[mf][nf][0] + b0;
      float y1 = acc[mf][nf][1] + b1;
      float y2 = acc[mf][nf][2] + b2;
      float y3 = acc[mf][nf][3] + b3;
      ushort4 pk = make_ushort4(f2b(y0), f2b(y1), f2b(y2), f2b(y3));
      *(ushort4*)(sbase + pl*128 + (cb2 ^ ((pl&7)<<4))) = pk;
      s1v[0]+=y0; s1v[1]+=y1; s1v[2]+=y2; s1v[3]+=y3;
      s2v[0]+=y0*y0; s2v[1]+=y1*y1; s2v[2]+=y2*y2; s2v[3]+=y3*y3;
    }
    #pragma unroll
    for (int off = 1; off < 16; off <<= 1) {
      #pragma unroll
      for (int r = 0; r < 4; ++r) {
        s1v[r] += __shfl_xor(s1v[r], off, 64);
        s2v[r] += __shfl_xor(s2v[r], off, 64);
      }
    }
    if (colp == 0) {
      #pragma unroll
      for (int r = 0; r < 4; ++r) {
        atomicAdd(&S1[co_b+r], s1v[r]);
        atomicAdd(&S2[co_b+r], s2v[r]);
      }
    }
  }
  __syncthreads();
  constexpr int OW = BM/8;     // uint4 chunks per output row
  for (int idx = tid; idx < NPOS*OW; idx += 256) {
    int r = idx / OW, c16 = idx - r*OW;
    const char* sbase = (c16*16 < 128) ? XsB : Raw;
    int cbb = (c16*16) & 127;
    uint4 v = *(const uint4*)(sbase + r*128 + (cbb ^ ((r&7)<<4)));
    *(uint4*)(out + (brow + p0 + r)*COUT + co0 + c16*8) = v;
  }
}

#define CONV_ARGS const __hip_bfloat16* in, const __hip_bfloat16* wb, const float* cb, \
                  const float* S1p, const float* S2p, const float* g, const float* be, \
                  __hip_bfloat16* out, float* S1, float* S2

__global__ __launch_bounds__(256, 2) void conv_l1(CONV_ARGS){ conv_impl<64,64,5,64,256>(in,wb,cb,S1p,S2p,g,be,out,S1,S2); }
__global__ __launch_bounds__(256, 2) void conv_l2(CONV_ARGS){ conv_impl<64,128,15,128,256>(in,wb,cb,S1p,S2p,g,be,out,S1,S2); }
__global__ __launch_bounds__(256, 2) void conv_l3(CONV_ARGS){ conv_impl<128,128,15,128,256>(in,wb,cb,S1p,S2p,g,be,out,S1,S2); }
__global__ __launch_bounds__(256, 2) void conv_l4(CONV_ARGS){ conv_impl<128,256,25,128,256>(in,wb,cb,S1p,S2p,g,be,out,S1,S2); }
__global__ __launch_bounds__(256, 2) void conv_l5(CONV_ARGS){ conv_impl<256,256,25,128,256>(in,wb,cb,S1p,S2p,g,be,out,S1,S2); }

// ---------- feat: sum over L of relu(bn(a5)) with in-kernel BN finalize ----------
__global__ __launch_bounds__(256)
void feat_accum(const __hip_bfloat16* __restrict__ a,
                const float* __restrict__ S1, const float* __restrict__ S2,
                const float* __restrict__ g, const float* __restrict__ be,
                float* __restrict__ feat)
{
  const int b = blockIdx.y, chunk = blockIdx.x, c = threadIdx.x;
  const float invN = 1.f / 65536.f;
  float mm = S1[c] * invN;
  float var = fmaxf(S2[c] * invN - mm*mm, 0.f);
  float sc = g[c] / sqrtf(var + 1e-5f);
  float sh = be[c] - mm * sc;
  float s = 0.f;
  const __hip_bfloat16* p = a + ((size_t)b*LSEQ + chunk*256)*256 + c;
  #pragma unroll 4
  for (int i = 0; i < 256; ++i)
    s += fmaxf(fmaf(__bfloat162float(p[(size_t)i*256]), sc, sh), 0.f);
  atomicAdd(&feat[b*256 + c], s);
}

// ---------- head: two 32x64x256 GEMVs ----------
__global__ __launch_bounds__(256)
void head_kernel(const float* __restrict__ feat, const float* __restrict__ wm,
                 const float* __restrict__ bm, const float* __restrict__ wv,
                 const float* __restrict__ bv, float* __restrict__ out)
{
  int idx = blockIdx.x*256 + threadIdx.x;
  int sel = idx >> 11, rem = idx & 2047, b = rem >> 6, j = rem & 63;
  const float* W = sel ? wv : wm;
  const float* bias = sel ? bv : bm;
  const float4* f = (const float4*)(feat + b*256);
  const float4* wr = (const float4*)(W + j*256);
  float acc = 0.f;
  #pragma unroll 4
  for (int c = 0; c < 64; ++c) {
    float4 a4 = f[c], w4 = wr[c];
    acc += a4.x*w4.x + a4.y*w4.y + a4.z*w4.z + a4.w*w4.w;
  }
  out[idx] = acc * (1.f/(float)LSEQ) + bias[j];
}

extern "C" void kernel_launch(void* const* d_in, const int* in_sizes, int n_in,
                              void* d_out, int out_size, void* d_ws, size_t ws_size,
                              hipStream_t stream)
{
  (void)in_sizes; (void)n_in; (void)out_size; (void)ws_size;
  const float* x = (const float*)d_in[0];
  const float *cw[6], *cbp[6], *bg[6], *bb[6];
  for (int i = 0; i < 6; i++){
    cw[i]=(const float*)d_in[1+4*i]; cbp[i]=(const float*)d_in[2+4*i];
    bg[i]=(const float*)d_in[3+4*i]; bb[i]=(const float*)d_in[4+4*i];
  }
  const float* wmh=(const float*)d_in[25]; const float* bmh=(const float*)d_in[26];
  const float* wvh=(const float*)d_in[27]; const float* bvh=(const float*)d_in[28];

  char* ws = (char*)d_ws;
  size_t off = 0;
  float* h0 = (float*)(ws+off);            off += (size_t)NB*LSEQ*4;   // unused (kept for layout)
  __hip_bfloat16* bufA = (__hip_bfloat16*)(ws+off); off += (size_t)NB*LSEQ*256*2;
  __hip_bfloat16* bufB = (__hip_bfloat16*)(ws+off); off += (size_t)NB*LSEQ*256*2;
  __hip_bfloat16* wb1 = (__hip_bfloat16*)(ws+off); off += (size_t)5*64*64*2;
  __hip_bfloat16* wb2 = (__hip_bfloat16*)(ws+off); off += (size_t)15*128*64*2;
  __hip_bfloat16* wb3 = (__hip_bfloat16*)(ws+off); off += (size_t)15*128*128*2;
  __hip_bfloat16* wb4 = (__hip_bfloat16*)(ws+off); off += (size_t)25*256*128*2;
  __hip_bfloat16* wb5 = (__hip_bfloat16*)(ws+off); off += (size_t)25*256*256*2;
  float* stats = (float*)(ws+off);         off += 3072*4;
  float* feat  = (float*)(ws+off);         off += (size_t)NB*256*4;   // contiguous with stats
  float* S1 = stats; float* S2 = stats + 1536;
  (void)h0;

  // blocks 0..43 zero stats+feat; blocks 44..875 transpose/convert weights (coalesced)
  prep_all<<<876, 256, 0, stream>>>(cw[1], cw[2], cw[3], cw[4], cw[5],
                                    wb1, wb2, wb3, wb4, wb5, stats);

  // fused: row preprocessing + conv0 (stats must be zeroed first)
  row_prep_c0<<<NB, 256, 0, stream>>>(x, cw[0], cbp[0], bufA, S1+0, S2+0);

  conv_l1<<<dim3(8,1,NB),256,0,stream>>>(
      bufA, wb1, cbp[1], S1+0, S2+0, bg[0], bb[0], bufB, S1+256, S2+256);

  conv_l2<<<dim3(8,1,NB),256,0,stream>>>(
      bufB, wb2, cbp[2], S1+256, S2+256, bg[1], bb[1], bufA, S1+512, S2+512);

  conv_l3<<<dim3(8,1,NB),256,0,stream>>>(
      bufA, wb3, cbp[3], S1+512, S2+512, bg[2], bb[2], bufB, S1+768, S2+768);

  conv_l4<<<dim3(8,2,NB),256,0,stream>>>(
      bufB, wb4, cbp[4], S1+768, S2+768, bg[3], bb[3], bufA, S1+1024, S2+1024);

  conv_l5<<<dim3(8,2,NB),256,0,stream>>>(
      bufA, wb5, cbp[5], S1+1024, S2+1024, bg[4], bb[4], bufB, S1+1280, S2+1280);

  feat_accum<<<dim3(8, NB), 256, 0, stream>>>(bufB, S1+1280, S2+1280, bg[5], bb[5], feat);
  head_kernel<<<16, 256, 0, stream>>>(feat, wmh, bmh, wvh, bvh, (float*)d_out);
}

// Round 20
// 784.167 us; speedup vs baseline: 1.0591x; 1.0305x over previous
//
#include <hip/hip_runtime.h>
#include <hip/hip_bf16.h>

#define LSEQ 2048
#define NB 32

typedef __attribute__((ext_vector_type(8))) short short8v;
typedef __attribute__((ext_vector_type(4))) float float4v;

// ---------- dtype helpers ----------
__device__ __forceinline__ unsigned short f2b(float f){
  __hip_bfloat16 h = __float2bfloat16(f);
  return *reinterpret_cast<unsigned short*>(&h);
}
__device__ __forceinline__ float b2f_bits(unsigned short u){
  unsigned int x = ((unsigned int)u) << 16; return __uint_as_float(x);
}

__device__ __forceinline__ float wave_min(float v){
  #pragma unroll
  for (int off = 32; off; off >>= 1) v = fminf(v, __shfl_xor(v, off, 64));
  return v;
}

// apply BN(scale,shift)+relu to 8 bf16 packed in uint4, repack to bf16
__device__ __forceinline__ uint4 bn_pack(uint4 g, const float* sc, const float* sh, int cbase){
  union { uint4 u; unsigned short us[8]; } in_, out_;
  in_.u = g;
  #pragma unroll
  for (int j = 0; j < 8; ++j){
    float v = b2f_bits(in_.us[j]);
    v = fmaxf(fmaf(v, sc[cbase+j], sh[cbase+j]), 0.f);
    out_.us[j] = f2b(v);
  }
  return out_.u;
}

// async 16B global -> LDS
__device__ __forceinline__ void gl_lds16(const void* g, void* l){
  __builtin_amdgcn_global_load_lds(
      (const __attribute__((address_space(1))) void*)g,
      (__attribute__((address_space(3))) void*)l, 16, 0, 0);
}

// ---------- merged prep + row_prep + conv0 ----------
// blocks 0..43: zero stats+feat; 44..875: weight transpose fp32->bf16 [t][co][ci];
// 876..907: row preprocessing (stats+find_peaks+normalize) + conv0 from LDS row,
//           conv0 stats written as per-batch PARTIALS (no atomics, no zero dep).
__global__ __launch_bounds__(256)
void prep_row(const float* __restrict__ x,
              const float* __restrict__ w0, const float* __restrict__ cb0,
              const float* __restrict__ w1, const float* __restrict__ w2,
              const float* __restrict__ w3, const float* __restrict__ w4,
              const float* __restrict__ w5,
              __hip_bfloat16* __restrict__ o1, __hip_bfloat16* __restrict__ o2,
              __hip_bfloat16* __restrict__ o3, __hip_bfloat16* __restrict__ o4,
              __hip_bfloat16* __restrict__ o5,
              float* __restrict__ zbuf,
              __hip_bfloat16* __restrict__ c0out,
              float* __restrict__ S0p1, float* __restrict__ S0p2)
{
  __shared__ alignas(16) char pool[25600];
  const int blk = blockIdx.x, tid = threadIdx.x;

  if (blk < 876) {
    // ---- prep path ----
    int b = blk;
    if (b < 44) { int i = b*256 + tid; if (i < 11264) zbuf[i] = 0.f; return; }
    b -= 44;
    float* tile = (float*)pool;
    const float* w; __hip_bfloat16* o; int COUT, CIN, K, co;
    if      (b < 64)  { w=w1; o=o1; COUT=64;  CIN=64;  K=5;  co=b;     }
    else if (b < 192) { w=w2; o=o2; COUT=128; CIN=64;  K=15; co=b-64;  }
    else if (b < 320) { w=w3; o=o3; COUT=128; CIN=128; K=15; co=b-192; }
    else if (b < 576) { w=w4; o=o4; COUT=256; CIN=128; K=25; co=b-320; }
    else              { w=w5; o=o5; COUT=256; CIN=256; K=25; co=b-576; }
    const int n = CIN * K;
    const float* src = w + (size_t)co * n;
    for (int i = tid; i < n; i += 256) tile[i] = src[i];        // tile[ci*K + t]
    __syncthreads();
    for (int i = tid; i < n; i += 256) {
      int t = i / CIN, ci = i - t*CIN;
      o[((size_t)t*COUT + co)*CIN + ci] = __float2bfloat16(tile[ci*K + t]);
    }
    return;
  }

  // ---- row path ----
  const int b = blk - 876;
  const int lane = tid & 63, wid = tid >> 6;
  float* xs_raw            = (float*)(pool + 0);          // (2048+18) floats
  unsigned char* st_raw    = (unsigned char*)(pool + 8264);
  unsigned char* peaks     = (unsigned char*)(pool + 10332);
  short* s_cand            = (short*)(pool + 12380);
  short* s_kept            = (short*)(pool + 14428);
  float* sw                = (float*)(pool + 14940);      // 320
  float* sb                = (float*)(pool + 16220);      // 64
  float (*redA)[64]        = (float(*)[64])(pool + 16476);
  float (*redB)[64]        = (float(*)[64])(pool + 17500);
  float* s_redA            = (float*)(pool + 18524);      // 4
  float* s_redB            = (float*)(pool + 18540);      // 4
  float* s_sc3             = (float*)(pool + 18556);      // mx, mean, std
  int*   s_int             = (int*)(pool + 18568);        // flag, cnt, kcnt
  float* xsp = xs_raw + 9;
  unsigned char* stp = st_raw + 9;

  const float* xr = x + (size_t)b * LSEQ;
  for (int i = tid; i < LSEQ; i += 256) xsp[i] = xr[i];
  for (int i = tid; i < 18; i += 256) {
    xs_raw[(i < 9) ? i : (LSEQ + i)] = -__builtin_inff();
    st_raw[(i < 9) ? i : (LSEQ + i)] = 2;
  }
  for (int i = tid; i < 320; i += 256) sw[i] = w0[i];
  if (tid < 64) sb[tid] = cb0[tid];
  if (tid == 0) { s_int[1] = 0; s_int[2] = 0; }
  __syncthreads();

  float vmax = -__builtin_inff(), vsum = 0.f;
  for (int i = tid; i < LSEQ; i += 256) { float v = xsp[i]; vmax = fmaxf(vmax, v); vsum += v; }
  #pragma unroll
  for (int off = 32; off; off >>= 1){
    vmax = fmaxf(vmax, __shfl_xor(vmax, off, 64));
    vsum += __shfl_xor(vsum, off, 64);
  }
  if (lane == 0){ s_redA[wid] = vmax; s_redB[wid] = vsum; }
  __syncthreads();
  if (tid == 0){
    s_sc3[0] = fmaxf(fmaxf(s_redA[0], s_redA[1]), fmaxf(s_redA[2], s_redA[3]));
    s_sc3[1] = (s_redB[0]+s_redB[1]+s_redB[2]+s_redB[3]) * (1.f/(float)LSEQ);
  }
  __syncthreads();
  const float m = s_sc3[1], mx = s_sc3[0];

  float vss = 0.f;
  for (int i = tid; i < LSEQ; i += 256){ float d = xsp[i]-m; vss += d*d; }
  #pragma unroll
  for (int off = 32; off; off >>= 1) vss += __shfl_xor(vss, off, 64);
  if (lane == 0) s_redA[wid] = vss;
  __syncthreads();
  if (tid == 0) s_sc3[2] = sqrtf((s_redA[0]+s_redA[1]+s_redA[2]+s_redA[3]) / (float)(LSEQ-1));
  __syncthreads();
  const float sd = s_sc3[2];

  const float hthr = 0.1f * mx;
  for (int i = tid; i < LSEQ; i += 256) {
    unsigned char c = 2;
    if (i >= 1 && i <= LSEQ-2) {
      float v = xsp[i];
      if ((v > xsp[i-1]) && (v > xsp[i+1]) && (v >= hthr)) {
        c = 0;
        int s = atomicAdd(&s_int[1], 1);
        if (s < 1024) s_cand[s] = (short)i;
      }
    }
    stp[i] = c; peaks[i] = 0;
  }
  __syncthreads();
  const int cnt = (s_int[1] < 1024) ? s_int[1] : 1024;

  for (int round = 0; round < 1024; ++round) {
    if (tid == 0) s_int[0] = 0;
    __syncthreads();
    int und = 0;
    for (int q = tid; q < cnt; q += 256) {
      int i = s_cand[q];
      if (stp[i] == 0) {
        float xi = xsp[i];
        bool anyK = false, allD = true;
        #pragma unroll
        for (int o = -9; o <= 9; ++o) {
          if (o == 0) continue;
          unsigned char s = stp[i+o];
          float xj = xsp[i+o];
          bool hi = (xj > xi) || (xj == xi && o < 0);
          anyK = anyK || (hi && s == 1);
          allD = allD && ((!hi) || s == 2);
        }
        unsigned char ns = anyK ? 2 : (allD ? 1 : 0);
        if (ns) stp[i] = ns; else und = 1;
      }
    }
    if (und) s_int[0] = 1;
    __syncthreads();
    if (!s_int[0]) break;
  }

  for (int q = tid; q < cnt; q += 256) {
    int i = s_cand[q];
    if (stp[i] == 1) { int s = atomicAdd(&s_int[2], 1); s_kept[s] = (short)i; }
  }
  __syncthreads();
  const int M = s_int[2];
  const float pthr = 0.05f * mx;

  for (int c = wid; c < M; c += 4) {
    int p = s_kept[c]; float xp = xsp[p];
    float lm = xp; bool done = false;
    for (int s = 0; !done; ++s) {
      int idx = p - 64*(s+1) + lane;
      float v = (idx >= 0) ? xsp[idx] : -__builtin_inff();
      unsigned long long mk = __ballot(v > xp);
      if (mk) {
        int hb = 63 - __builtin_clzll(mk);
        lm = fminf(lm, (lane > hb) ? v : __builtin_inff());
        done = true;
      } else {
        lm = fminf(lm, (idx >= 0) ? v : __builtin_inff());
        done = (p - 64*(s+1) <= 0);
      }
    }
    float lmin = wave_min(lm);
    float rm = xp; done = false;
    for (int s = 0; !done; ++s) {
      int idx = p + 1 + 64*s + lane;
      float v = (idx < LSEQ) ? xsp[idx] : -__builtin_inff();
      unsigned long long mk = __ballot(v > xp);
      if (mk) {
        int lb_ = __builtin_ctzll(mk);
        rm = fminf(rm, (lane < lb_) ? v : __builtin_inff());
        done = true;
      } else {
        rm = fminf(rm, (idx < LSEQ) ? v : __builtin_inff());
        done = (p + 64 + 64*s >= LSEQ-1);
      }
    }
    float rmin = wave_min(rm);
    if (lane == 0 && (xp - fmaxf(lmin, rmin)) >= pthr) peaks[p] = 1;
  }
  __syncthreads();

  // normalize in place
  const float inv = 1.f / (sd + 1e-5f);
  for (int i = tid; i < LSEQ; i += 256) {
    float w_ = 1.f + 0.1f * (float)peaks[i];
    xsp[i] = (w_ * (xsp[i] - m)) * inv;
  }
  __syncthreads();

  // conv0 from LDS row: thread owns co = tid&63, positions pgrp,pgrp+4,...
  const int co = tid & 63, pgrp = tid >> 6;
  float wk0 = sw[co*5+0], wk1 = sw[co*5+1], wk2 = sw[co*5+2],
        wk3 = sw[co*5+3], wk4 = sw[co*5+4];
  const float bias = sb[co];
  float s1 = 0.f, s2 = 0.f;
  __hip_bfloat16* orow = c0out + (size_t)b * LSEQ * 64 + co;
  for (int pos = pgrp; pos < LSEQ; pos += 4) {
    float x0 = (pos-2 >= 0)   ? xsp[pos-2] : 0.f;
    float x1 = (pos-1 >= 0)   ? xsp[pos-1] : 0.f;
    float x2 = xsp[pos];
    float x3 = (pos+1 < LSEQ) ? xsp[pos+1] : 0.f;
    float x4 = (pos+2 < LSEQ) ? xsp[pos+2] : 0.f;
    float y = bias;
    y = fmaf(wk0, x0, y);
    y = fmaf(wk1, x1, y);
    y = fmaf(wk2, x2, y);
    y = fmaf(wk3, x3, y);
    y = fmaf(wk4, x4, y);
    orow[(size_t)pos*64] = __float2bfloat16(y);
    s1 += y; s2 += y*y;
  }
  redA[pgrp][co] = s1; redB[pgrp][co] = s2;
  __syncthreads();
  if (tid < 64) {
    float a  = redA[0][tid]+redA[1][tid]+redA[2][tid]+redA[3][tid];
    float bb = redB[0][tid]+redB[1][tid]+redB[2][tid]+redB[3][tid];
    S0p1[b*64 + tid] = a;      // per-batch partials, no atomics
    S0p2[b*64 + tid] = bb;
  }
}

// ---------- MFMA implicit-GEMM conv, 16x16x32, tap-interleaved async DMA ----------
// NPART: number of partial-sum rows in S1p/S2p ([NPART][CIN]); 1 = plain.
template<int CIN, int COUT, int K, int BM, int NPOS, int NPART = 1>
__device__ __forceinline__
void conv_impl(const __hip_bfloat16* __restrict__ in,
               const __hip_bfloat16* __restrict__ wb,
               const float* __restrict__ cb,
               const float* __restrict__ S1p, const float* __restrict__ S2p,
               const float* __restrict__ g, const float* __restrict__ be,
               __hip_bfloat16* __restrict__ out,
               float* __restrict__ S1, float* __restrict__ S2)
{
  constexpr int PAD = K/2, XR = NPOS + K - 1;
  constexpr int WM_T = BM/2, MF = WM_T/16;
  constexpr int WN_T = NPOS/2, NF = WN_T/16;
  constexpr int NIDX = XR*8;
  constexpr int NCH = (NIDX + 255)/256;

  __shared__ float s_sc[CIN], s_sh[CIN];
  __shared__ alignas(16) char XsB[XR*128];       // swizzled [pos][64ci]
  __shared__ alignas(16) char Raw[NCH*4096];     // linear DMA landing zone

  const int tid = threadIdx.x;
  const int lane = tid & 63;
  const int wid = tid >> 6;
  const int wm = wid >> 1, wn = wid & 1;
  const int b = blockIdx.z;
  const int p0 = blockIdx.x * NPOS;
  const int co0 = blockIdx.y * BM;
  const int colp = lane & 15, rgrp = lane >> 4;

  const size_t brow = (size_t)b * LSEQ;

  auto dma_one = [&](int cic, int q){
    int idx = tid + q*256;
    int r = idx >> 3, ch = idx & 7;
    int gp = p0 - PAD + r;
    int gpc = gp < 0 ? 0 : (gp > LSEQ-1 ? LSEQ-1 : gp);
    gl_lds16(in + (brow + gpc)*CIN + cic + ch*8, Raw + idx*16);
  };
  auto issue_dma = [&](int cic){
    #pragma unroll
    for (int q = 0; q < NCH; ++q) dma_one(cic, q);
  };

  issue_dma(0);     // first chunk's DMA flies under the BN-finalize preamble

  const float invN = 1.f / 65536.f;
  for (int i = tid; i < CIN; i += 256) {
    float a = 0.f, bq = 0.f;
    for (int p = 0; p < NPART; ++p) { a += S1p[p*CIN + i]; bq += S2p[p*CIN + i]; }
    float mm = a * invN;
    float var = fmaxf(bq * invN - mm*mm, 0.f);
    float sc = g[i] / sqrtf(var + 1e-5f);
    s_sc[i] = sc;
    s_sh[i] = be[i] - mm * sc;
  }

  float4v acc[MF][NF];
  #pragma unroll
  for (int mf = 0; mf < MF; ++mf) {
    #pragma unroll
    for (int nf = 0; nf < NF; ++nf) acc[mf][nf] = (float4v){0.f,0.f,0.f,0.f};
  }

  const __hip_bfloat16* wlane = wb + ((size_t)(co0 + wm*WM_T + colp))*CIN + rgrp*8;

  auto transform = [&](int cic){
    #pragma unroll
    for (int q = 0; q < NCH; ++q) {
      int idx = tid + q*256;
      if (idx < NIDX) {
        int r = idx >> 3, ch = idx & 7;
        int gp = p0 - PAD + r;
        uint4 v = make_uint4(0u,0u,0u,0u);
        if (gp >= 0 && gp < LSEQ) {
          v = *(const uint4*)(Raw + idx*16);
          v = bn_pack(v, s_sc, s_sh, cic + ch*8);
        }
        *(uint4*)(XsB + r*128 + ((ch*16) ^ ((r&7)<<4))) = v;
      }
    }
  };

  for (int cic = 0; cic < CIN; cic += 64) {
    __syncthreads();            // prev compute done with XsB; DMA long complete
    transform(cic);
    __syncthreads();            // XsB visible; Raw free for next chunk's DMA
    const bool nxtc = (cic + 64 < CIN);
    const int nc = cic + 64;

    const __hip_bfloat16* wch = wlane + cic;

    auto wfrag = [&](short8v (&dst)[2][MF], int tap) {
      #pragma unroll
      for (int kk = 0; kk < 2; ++kk) {
        #pragma unroll
        for (int mf = 0; mf < MF; ++mf) {
          dst[kk][mf] = *(const short8v*)(wch + ((size_t)tap*COUT + mf*16)*CIN + kk*32);
        }
      }
    };
    auto do_tap = [&](short8v (&cur)[2][MF], short8v (&nxt)[2][MF], int t) {
      if (t+1 < K) wfrag(nxt, t+1);       // prefetch next tap's weights
      if (nxtc && t < NCH) dma_one(nc, t); // interleave next-chunk DMA, 1 batch/tap
      __builtin_amdgcn_s_setprio(1);
      #pragma unroll
      for (int kk = 0; kk < 2; ++kk) {
        short8v bfr[NF];
        #pragma unroll
        for (int nf = 0; nf < NF; ++nf) {
          int rr = wn*WN_T + nf*16 + colp + t;
          bfr[nf] = *(const short8v*)(XsB + rr*128 + ((kk*64 + rgrp*16) ^ ((rr&7)<<4)));
        }
        #pragma unroll
        for (int mf = 0; mf < MF; ++mf) {
          #pragma unroll
          for (int nf = 0; nf < NF; ++nf) {
            acc[mf][nf] = __builtin_amdgcn_mfma_f32_16x16x32_bf16(cur[kk][mf], bfr[nf], acc[mf][nf], 0, 0, 0);
          }
        }
      }
      __builtin_amdgcn_s_setprio(0);
    };
    short8v afE[2][MF], afO[2][MF];
    wfrag(afE, 0);
    for (int t = 0; t < K; t += 2) {
      do_tap(afE, afO, t);
      if (t+1 < K) do_tap(afO, afE, t+1);
    }
    if (nxtc) {                            // leftover batches if K < NCH
      for (int q = K; q < NCH; ++q) dma_one(nc, q);
    }
  }

  // staged coalesced epilogue (co-half0 -> XsB, co-half1 -> Raw)
  __syncthreads();
  #pragma unroll
  for (int mf = 0; mf < MF; ++mf) {
    int co_rel = wm*WM_T + mf*16 + rgrp*4;
    int co_b = co0 + co_rel;
    float b0 = cb[co_b+0], b1 = cb[co_b+1], b2 = cb[co_b+2], b3 = cb[co_b+3];
    float s1v[4] = {0,0,0,0}, s2v[4] = {0,0,0,0};
    char* sbase = (co_rel*2 < 128) ? XsB : Raw;
    int cb2 = (co_rel*2) & 127;
    #pragma unroll
    for (int nf = 0; nf < NF; ++nf) {
      int pl = wn*WN_T + nf*16 + colp;
      float y0 = acc[mf][nf][0] + b0;
      float y1 = acc[mf][nf][1] + b1;
      float y2 = acc[mf][nf][2] + b2;
      float y3 = acc[mf][nf][3] + b3;
      ushort4 pk = make_ushort4(f2b(y0), f2b(y1), f2b(y2), f2b(y3));
      *(ushort4*)(sbase + pl*128 + (cb2 ^ ((pl&7)<<4))) = pk;
      s1v[0]+=y0; s1v[1]+=y1; s1v[2]+=y2; s1v[3]+=y3;
      s2v[0]+=y0*y0; s2v[1]+=y1*y1; s2v[2]+=y2*y2; s2v[3]+=y3*y3;
    }
    #pragma unroll
    for (int off = 1; off < 16; off <<= 1) {
      #pragma unroll
      for (int r = 0; r < 4; ++r) {
        s1v[r] += __shfl_xor(s1v[r], off, 64);
        s2v[r] += __shfl_xor(s2v[r], off, 64);
      }
    }
    if (colp == 0) {
      #pragma unroll
      for (int r = 0; r < 4; ++r) {
        atomicAdd(&S1[co_b+r], s1v[r]);
        atomicAdd(&S2[co_b+r], s2v[r]);
      }
    }
  }
  __syncthreads();
  constexpr int OW = BM/8;     // uint4 chunks per output row
  for (int idx = tid; idx < NPOS*OW; idx += 256) {
    int r = idx / OW, c16 = idx - r*OW;
    const char* sbase = (c16*16 < 128) ? XsB : Raw;
    int cbb = (c16*16) & 127;
    uint4 v = *(const uint4*)(sbase + r*128 + (cbb ^ ((r&7)<<4)));
    *(uint4*)(out + (brow + p0 + r)*COUT + co0 + c16*8) = v;
  }
}

#define CONV_ARGS const __hip_bfloat16* in, const __hip_bfloat16* wb, const float* cb, \
                  const float* S1p, const float* S2p, const float* g, const float* be, \
                  __hip_bfloat16* out, float* S1, float* S2

__global__ __launch_bounds__(256, 2) void conv_l1(CONV_ARGS){ conv_impl<64,64,5,64,256,32>(in,wb,cb,S1p,S2p,g,be,out,S1,S2); }
__global__ __launch_bounds__(256, 2) void conv_l2(CONV_ARGS){ conv_impl<64,128,15,128,256>(in,wb,cb,S1p,S2p,g,be,out,S1,S2); }
__global__ __launch_bounds__(256, 2) void conv_l3(CONV_ARGS){ conv_impl<128,128,15,128,256>(in,wb,cb,S1p,S2p,g,be,out,S1,S2); }
__global__ __launch_bounds__(256, 2) void conv_l4(CONV_ARGS){ conv_impl<128,256,25,128,256>(in,wb,cb,S1p,S2p,g,be,out,S1,S2); }
__global__ __launch_bounds__(256, 2) void conv_l5(CONV_ARGS){ conv_impl<256,256,25,128,256>(in,wb,cb,S1p,S2p,g,be,out,S1,S2); }

// ---------- feat: sum over L of relu(bn(a5)) with in-kernel BN finalize ----------
__global__ __launch_bounds__(256)
void feat_accum(const __hip_bfloat16* __restrict__ a,
                const float* __restrict__ S1, const float* __restrict__ S2,
                const float* __restrict__ g, const float* __restrict__ be,
                float* __restrict__ feat)
{
  const int b = blockIdx.y, chunk = blockIdx.x, c = threadIdx.x;
  const float invN = 1.f / 65536.f;
  float mm = S1[c] * invN;
  float var = fmaxf(S2[c] * invN - mm*mm, 0.f);
  float sc = g[c] / sqrtf(var + 1e-5f);
  float sh = be[c] - mm * sc;
  float s = 0.f;
  const __hip_bfloat16* p = a + ((size_t)b*LSEQ + chunk*256)*256 + c;
  #pragma unroll 4
  for (int i = 0; i < 256; ++i)
    s += fmaxf(fmaf(__bfloat162float(p[(size_t)i*256]), sc, sh), 0.f);
  atomicAdd(&feat[b*256 + c], s);
}

// ---------- head: two 32x64x256 GEMVs ----------
__global__ __launch_bounds__(256)
void head_kernel(const float* __restrict__ feat, const float* __restrict__ wm,
                 const float* __restrict__ bm, const float* __restrict__ wv,
                 const float* __restrict__ bv, float* __restrict__ out)
{
  int idx = blockIdx.x*256 + threadIdx.x;
  int sel = idx >> 11, rem = idx & 2047, b = rem >> 6, j = rem & 63;
  const float* W = sel ? wv : wm;
  const float* bias = sel ? bv : bm;
  const float4* f = (const float4*)(feat + b*256);
  const float4* wr = (const float4*)(W + j*256);
  float acc = 0.f;
  #pragma unroll 4
  for (int c = 0; c < 64; ++c) {
    float4 a4 = f[c], w4 = wr[c];
    acc += a4.x*w4.x + a4.y*w4.y + a4.z*w4.z + a4.w*w4.w;
  }
  out[idx] = acc * (1.f/(float)LSEQ) + bias[j];
}

extern "C" void kernel_launch(void* const* d_in, const int* in_sizes, int n_in,
                              void* d_out, int out_size, void* d_ws, size_t ws_size,
                              hipStream_t stream)
{
  (void)in_sizes; (void)n_in; (void)out_size; (void)ws_size;
  const float* x = (const float*)d_in[0];
  const float *cw[6], *cbp[6], *bg[6], *bb[6];
  for (int i = 0; i < 6; i++){
    cw[i]=(const float*)d_in[1+4*i]; cbp[i]=(const float*)d_in[2+4*i];
    bg[i]=(const float*)d_in[3+4*i]; bb[i]=(const float*)d_in[4+4*i];
  }
  const float* wmh=(const float*)d_in[25]; const float* bmh=(const float*)d_in[26];
  const float* wvh=(const float*)d_in[27]; const float* bvh=(const float*)d_in[28];

  char* ws = (char*)d_ws;
  size_t off = 0;
  float* h0 = (float*)(ws+off);            off += (size_t)NB*LSEQ*4;   // unused (kept for layout)
  __hip_bfloat16* bufA = (__hip_bfloat16*)(ws+off); off += (size_t)NB*LSEQ*256*2;
  __hip_bfloat16* bufB = (__hip_bfloat16*)(ws+off); off += (size_t)NB*LSEQ*256*2;
  __hip_bfloat16* wb1 = (__hip_bfloat16*)(ws+off); off += (size_t)5*64*64*2;
  __hip_bfloat16* wb2 = (__hip_bfloat16*)(ws+off); off += (size_t)15*128*64*2;
  __hip_bfloat16* wb3 = (__hip_bfloat16*)(ws+off); off += (size_t)15*128*128*2;
  __hip_bfloat16* wb4 = (__hip_bfloat16*)(ws+off); off += (size_t)25*256*128*2;
  __hip_bfloat16* wb5 = (__hip_bfloat16*)(ws+off); off += (size_t)25*256*256*2;
  float* stats = (float*)(ws+off);         off += 3072*4;
  float* feat  = (float*)(ws+off);         off += (size_t)NB*256*4;   // contiguous with stats
  float* S0p1  = (float*)(ws+off);         off += (size_t)NB*64*4;    // conv0 partials
  float* S0p2  = (float*)(ws+off);         off += (size_t)NB*64*4;
  float* S1 = stats; float* S2 = stats + 1536;
  (void)h0;

  // merged: zero stats+feat, weight transpose, row preprocessing + conv0
  prep_row<<<908, 256, 0, stream>>>(x, cw[0], cbp[0],
                                    cw[1], cw[2], cw[3], cw[4], cw[5],
                                    wb1, wb2, wb3, wb4, wb5, stats,
                                    bufA, S0p1, S0p2);

  conv_l1<<<dim3(8,1,NB),256,0,stream>>>(
      bufA, wb1, cbp[1], S0p1, S0p2, bg[0], bb[0], bufB, S1+256, S2+256);

  conv_l2<<<dim3(8,1,NB),256,0,stream>>>(
      bufB, wb2, cbp[2], S1+256, S2+256, bg[1], bb[1], bufA, S1+512, S2+512);

  conv_l3<<<dim3(8,1,NB),256,0,stream>>>(
      bufA, wb3, cbp[3], S1+512, S2+512, bg[2], bb[2], bufB, S1+768, S2+768);

  conv_l4<<<dim3(8,2,NB),256,0,stream>>>(
      bufB, wb4, cbp[4], S1+768, S2+768, bg[3], bb[3], bufA, S1+1024, S2+1024);

  conv_l5<<<dim3(8,2,NB),256,0,stream>>>(
      bufA, wb5, cbp[5], S1+1024, S2+1024, bg[4], bb[4], bufB, S1+1280, S2+1280);

  feat_accum<<<dim3(8, NB), 256, 0, stream>>>(bufB, S1+1280, S2+1280, bg[5], bb[5], feat);
  head_kernel<<<16, 256, 0, stream>>>(feat, wmh, bmh, wvh, bvh, (float*)d_out);
}

// Round 21
// 779.430 us; speedup vs baseline: 1.0655x; 1.0061x over previous
//
#include <hip/hip_runtime.h>
#include <hip/hip_bf16.h>

#define LSEQ 2048
#define NB 32

typedef __attribute__((ext_vector_type(8))) short short8v;
typedef __attribute__((ext_vector_type(4))) float float4v;

// ---------- dtype helpers ----------
__device__ __forceinline__ unsigned short f2b(float f){
  __hip_bfloat16 h = __float2bfloat16(f);
  return *reinterpret_cast<unsigned short*>(&h);
}
__device__ __forceinline__ float b2f_bits(unsigned short u){
  unsigned int x = ((unsigned int)u) << 16; return __uint_as_float(x);
}

__device__ __forceinline__ float wave_min(float v){
  #pragma unroll
  for (int off = 32; off; off >>= 1) v = fminf(v, __shfl_xor(v, off, 64));
  return v;
}

// apply BN(scale,shift)+relu to 8 bf16 packed in uint4, repack to bf16
__device__ __forceinline__ uint4 bn_pack(uint4 g, const float* sc, const float* sh, int cbase){
  union { uint4 u; unsigned short us[8]; } in_, out_;
  in_.u = g;
  #pragma unroll
  for (int j = 0; j < 8; ++j){
    float v = b2f_bits(in_.us[j]);
    v = fmaxf(fmaf(v, sc[cbase+j], sh[cbase+j]), 0.f);
    out_.us[j] = f2b(v);
  }
  return out_.u;
}

// async 16B global -> LDS
__device__ __forceinline__ void gl_lds16(const void* g, void* l){
  __builtin_amdgcn_global_load_lds(
      (const __attribute__((address_space(1))) void*)g,
      (__attribute__((address_space(3))) void*)l, 16, 0, 0);
}

// ---------- merged prep + row_prep + conv0 ----------
// blocks 0..43: zero stats + d_out; 44..875: weight transpose fp32->bf16 [t][co][ci];
// 876..907: row preprocessing (stats+find_peaks+normalize) + conv0 from LDS row,
//           conv0 stats written as per-batch PARTIALS (no atomics, no zero dep).
__global__ __launch_bounds__(256)
void prep_row(const float* __restrict__ x,
              const float* __restrict__ w0, const float* __restrict__ cb0,
              const float* __restrict__ w1, const float* __restrict__ w2,
              const float* __restrict__ w3, const float* __restrict__ w4,
              const float* __restrict__ w5,
              __hip_bfloat16* __restrict__ o1, __hip_bfloat16* __restrict__ o2,
              __hip_bfloat16* __restrict__ o3, __hip_bfloat16* __restrict__ o4,
              __hip_bfloat16* __restrict__ o5,
              float* __restrict__ zbuf, float* __restrict__ dout,
              __hip_bfloat16* __restrict__ c0out,
              float* __restrict__ S0p1, float* __restrict__ S0p2)
{
  __shared__ alignas(16) char pool[25600];
  const int blk = blockIdx.x, tid = threadIdx.x;

  if (blk < 876) {
    // ---- prep path ----
    int b = blk;
    if (b < 44) {
      int i = b*256 + tid;
      if (i < 3072) zbuf[i] = 0.f;     // conv1..5 stats
      if (i < 4096) dout[i] = 0.f;     // output accumulators (harness poisons d_out)
      return;
    }
    b -= 44;
    float* tile = (float*)pool;
    const float* w; __hip_bfloat16* o; int COUT, CIN, K, co;
    if      (b < 64)  { w=w1; o=o1; COUT=64;  CIN=64;  K=5;  co=b;     }
    else if (b < 192) { w=w2; o=o2; COUT=128; CIN=64;  K=15; co=b-64;  }
    else if (b < 320) { w=w3; o=o3; COUT=128; CIN=128; K=15; co=b-192; }
    else if (b < 576) { w=w4; o=o4; COUT=256; CIN=128; K=25; co=b-320; }
    else              { w=w5; o=o5; COUT=256; CIN=256; K=25; co=b-576; }
    const int n = CIN * K;
    const float* src = w + (size_t)co * n;
    for (int i = tid; i < n; i += 256) tile[i] = src[i];        // tile[ci*K + t]
    __syncthreads();
    for (int i = tid; i < n; i += 256) {
      int t = i / CIN, ci = i - t*CIN;
      o[((size_t)t*COUT + co)*CIN + ci] = __float2bfloat16(tile[ci*K + t]);
    }
    return;
  }

  // ---- row path ----
  const int b = blk - 876;
  const int lane = tid & 63, wid = tid >> 6;
  float* xs_raw            = (float*)(pool + 0);          // (2048+18) floats
  unsigned char* st_raw    = (unsigned char*)(pool + 8264);
  unsigned char* peaks     = (unsigned char*)(pool + 10332);
  short* s_cand            = (short*)(pool + 12380);
  short* s_kept            = (short*)(pool + 14428);
  float* sw                = (float*)(pool + 14940);      // 320
  float* sb                = (float*)(pool + 16220);      // 64
  float (*redA)[64]        = (float(*)[64])(pool + 16476);
  float (*redB)[64]        = (float(*)[64])(pool + 17500);
  float* s_redA            = (float*)(pool + 18524);      // 4
  float* s_redB            = (float*)(pool + 18540);      // 4
  float* s_sc3             = (float*)(pool + 18556);      // mx, mean, std
  int*   s_int             = (int*)(pool + 18568);        // flag, cnt, kcnt
  float* xsp = xs_raw + 9;
  unsigned char* stp = st_raw + 9;

  const float* xr = x + (size_t)b * LSEQ;
  for (int i = tid; i < LSEQ; i += 256) xsp[i] = xr[i];
  for (int i = tid; i < 18; i += 256) {
    xs_raw[(i < 9) ? i : (LSEQ + i)] = -__builtin_inff();
    st_raw[(i < 9) ? i : (LSEQ + i)] = 2;
  }
  for (int i = tid; i < 320; i += 256) sw[i] = w0[i];
  if (tid < 64) sb[tid] = cb0[tid];
  if (tid == 0) { s_int[1] = 0; s_int[2] = 0; }
  __syncthreads();

  float vmax = -__builtin_inff(), vsum = 0.f;
  for (int i = tid; i < LSEQ; i += 256) { float v = xsp[i]; vmax = fmaxf(vmax, v); vsum += v; }
  #pragma unroll
  for (int off = 32; off; off >>= 1){
    vmax = fmaxf(vmax, __shfl_xor(vmax, off, 64));
    vsum += __shfl_xor(vsum, off, 64);
  }
  if (lane == 0){ s_redA[wid] = vmax; s_redB[wid] = vsum; }
  __syncthreads();
  if (tid == 0){
    s_sc3[0] = fmaxf(fmaxf(s_redA[0], s_redA[1]), fmaxf(s_redA[2], s_redA[3]));
    s_sc3[1] = (s_redB[0]+s_redB[1]+s_redB[2]+s_redB[3]) * (1.f/(float)LSEQ);
  }
  __syncthreads();
  const float m = s_sc3[1], mx = s_sc3[0];

  float vss = 0.f;
  for (int i = tid; i < LSEQ; i += 256){ float d = xsp[i]-m; vss += d*d; }
  #pragma unroll
  for (int off = 32; off; off >>= 1) vss += __shfl_xor(vss, off, 64);
  if (lane == 0) s_redA[wid] = vss;
  __syncthreads();
  if (tid == 0) s_sc3[2] = sqrtf((s_redA[0]+s_redA[1]+s_redA[2]+s_redA[3]) / (float)(LSEQ-1));
  __syncthreads();
  const float sd = s_sc3[2];

  const float hthr = 0.1f * mx;
  for (int i = tid; i < LSEQ; i += 256) {
    unsigned char c = 2;
    if (i >= 1 && i <= LSEQ-2) {
      float v = xsp[i];
      if ((v > xsp[i-1]) && (v > xsp[i+1]) && (v >= hthr)) {
        c = 0;
        int s = atomicAdd(&s_int[1], 1);
        if (s < 1024) s_cand[s] = (short)i;
      }
    }
    stp[i] = c; peaks[i] = 0;
  }
  __syncthreads();
  const int cnt = (s_int[1] < 1024) ? s_int[1] : 1024;

  for (int round = 0; round < 1024; ++round) {
    if (tid == 0) s_int[0] = 0;
    __syncthreads();
    int und = 0;
    for (int q = tid; q < cnt; q += 256) {
      int i = s_cand[q];
      if (stp[i] == 0) {
        float xi = xsp[i];
        bool anyK = false, allD = true;
        #pragma unroll
        for (int o = -9; o <= 9; ++o) {
          if (o == 0) continue;
          unsigned char s = stp[i+o];
          float xj = xsp[i+o];
          bool hi = (xj > xi) || (xj == xi && o < 0);
          anyK = anyK || (hi && s == 1);
          allD = allD && ((!hi) || s == 2);
        }
        unsigned char ns = anyK ? 2 : (allD ? 1 : 0);
        if (ns) stp[i] = ns; else und = 1;
      }
    }
    if (und) s_int[0] = 1;
    __syncthreads();
    if (!s_int[0]) break;
  }

  for (int q = tid; q < cnt; q += 256) {
    int i = s_cand[q];
    if (stp[i] == 1) { int s = atomicAdd(&s_int[2], 1); s_kept[s] = (short)i; }
  }
  __syncthreads();
  const int M = s_int[2];
  const float pthr = 0.05f * mx;

  for (int c = wid; c < M; c += 4) {
    int p = s_kept[c]; float xp = xsp[p];
    float lm = xp; bool done = false;
    for (int s = 0; !done; ++s) {
      int idx = p - 64*(s+1) + lane;
      float v = (idx >= 0) ? xsp[idx] : -__builtin_inff();
      unsigned long long mk = __ballot(v > xp);
      if (mk) {
        int hb = 63 - __builtin_clzll(mk);
        lm = fminf(lm, (lane > hb) ? v : __builtin_inff());
        done = true;
      } else {
        lm = fminf(lm, (idx >= 0) ? v : __builtin_inff());
        done = (p - 64*(s+1) <= 0);
      }
    }
    float lmin = wave_min(lm);
    float rm = xp; done = false;
    for (int s = 0; !done; ++s) {
      int idx = p + 1 + 64*s + lane;
      float v = (idx < LSEQ) ? xsp[idx] : -__builtin_inff();
      unsigned long long mk = __ballot(v > xp);
      if (mk) {
        int lb_ = __builtin_ctzll(mk);
        rm = fminf(rm, (lane < lb_) ? v : __builtin_inff());
        done = true;
      } else {
        rm = fminf(rm, (idx < LSEQ) ? v : __builtin_inff());
        done = (p + 64 + 64*s >= LSEQ-1);
      }
    }
    float rmin = wave_min(rm);
    if (lane == 0 && (xp - fmaxf(lmin, rmin)) >= pthr) peaks[p] = 1;
  }
  __syncthreads();

  // normalize in place
  const float inv = 1.f / (sd + 1e-5f);
  for (int i = tid; i < LSEQ; i += 256) {
    float w_ = 1.f + 0.1f * (float)peaks[i];
    xsp[i] = (w_ * (xsp[i] - m)) * inv;
  }
  __syncthreads();

  // conv0 from LDS row: thread owns co = tid&63, positions pgrp,pgrp+4,...
  const int co = tid & 63, pgrp = tid >> 6;
  float wk0 = sw[co*5+0], wk1 = sw[co*5+1], wk2 = sw[co*5+2],
        wk3 = sw[co*5+3], wk4 = sw[co*5+4];
  const float bias = sb[co];
  float s1 = 0.f, s2 = 0.f;
  __hip_bfloat16* orow = c0out + (size_t)b * LSEQ * 64 + co;
  for (int pos = pgrp; pos < LSEQ; pos += 4) {
    float x0 = (pos-2 >= 0)   ? xsp[pos-2] : 0.f;
    float x1 = (pos-1 >= 0)   ? xsp[pos-1] : 0.f;
    float x2 = xsp[pos];
    float x3 = (pos+1 < LSEQ) ? xsp[pos+1] : 0.f;
    float x4 = (pos+2 < LSEQ) ? xsp[pos+2] : 0.f;
    float y = bias;
    y = fmaf(wk0, x0, y);
    y = fmaf(wk1, x1, y);
    y = fmaf(wk2, x2, y);
    y = fmaf(wk3, x3, y);
    y = fmaf(wk4, x4, y);
    orow[(size_t)pos*64] = __float2bfloat16(y);
    s1 += y; s2 += y*y;
  }
  redA[pgrp][co] = s1; redB[pgrp][co] = s2;
  __syncthreads();
  if (tid < 64) {
    float a  = redA[0][tid]+redA[1][tid]+redA[2][tid]+redA[3][tid];
    float bb = redB[0][tid]+redB[1][tid]+redB[2][tid]+redB[3][tid];
    S0p1[b*64 + tid] = a;      // per-batch partials, no atomics
    S0p2[b*64 + tid] = bb;
  }
}

// ---------- MFMA implicit-GEMM conv, 16x16x32, tap-interleaved async DMA ----------
// NPART: number of partial-sum rows in S1p/S2p ([NPART][CIN]); 1 = plain.
template<int CIN, int COUT, int K, int BM, int NPOS, int NPART = 1>
__device__ __forceinline__
void conv_impl(const __hip_bfloat16* __restrict__ in,
               const __hip_bfloat16* __restrict__ wb,
               const float* __restrict__ cb,
               const float* __restrict__ S1p, const float* __restrict__ S2p,
               const float* __restrict__ g, const float* __restrict__ be,
               __hip_bfloat16* __restrict__ out,
               float* __restrict__ S1, float* __restrict__ S2)
{
  constexpr int PAD = K/2, XR = NPOS + K - 1;
  constexpr int WM_T = BM/2, MF = WM_T/16;
  constexpr int WN_T = NPOS/2, NF = WN_T/16;
  constexpr int NIDX = XR*8;
  constexpr int NCH = (NIDX + 255)/256;

  __shared__ float s_sc[CIN], s_sh[CIN];
  __shared__ alignas(16) char XsB[XR*128];       // swizzled [pos][64ci]
  __shared__ alignas(16) char Raw[NCH*4096];     // linear DMA landing zone

  const int tid = threadIdx.x;
  const int lane = tid & 63;
  const int wid = tid >> 6;
  const int wm = wid >> 1, wn = wid & 1;
  const int b = blockIdx.z;
  const int p0 = blockIdx.x * NPOS;
  const int co0 = blockIdx.y * BM;
  const int colp = lane & 15, rgrp = lane >> 4;

  const size_t brow = (size_t)b * LSEQ;

  auto dma_one = [&](int cic, int q){
    int idx = tid + q*256;
    int r = idx >> 3, ch = idx & 7;
    int gp = p0 - PAD + r;
    int gpc = gp < 0 ? 0 : (gp > LSEQ-1 ? LSEQ-1 : gp);
    gl_lds16(in + (brow + gpc)*CIN + cic + ch*8, Raw + idx*16);
  };
  auto issue_dma = [&](int cic){
    #pragma unroll
    for (int q = 0; q < NCH; ++q) dma_one(cic, q);
  };

  issue_dma(0);     // first chunk's DMA flies under the BN-finalize preamble

  const float invN = 1.f / 65536.f;
  for (int i = tid; i < CIN; i += 256) {
    float a = 0.f, bq = 0.f;
    for (int p = 0; p < NPART; ++p) { a += S1p[p*CIN + i]; bq += S2p[p*CIN + i]; }
    float mm = a * invN;
    float var = fmaxf(bq * invN - mm*mm, 0.f);
    float sc = g[i] / sqrtf(var + 1e-5f);
    s_sc[i] = sc;
    s_sh[i] = be[i] - mm * sc;
  }

  float4v acc[MF][NF];
  #pragma unroll
  for (int mf = 0; mf < MF; ++mf) {
    #pragma unroll
    for (int nf = 0; nf < NF; ++nf) acc[mf][nf] = (float4v){0.f,0.f,0.f,0.f};
  }

  const __hip_bfloat16* wlane = wb + ((size_t)(co0 + wm*WM_T + colp))*CIN + rgrp*8;

  auto transform = [&](int cic){
    #pragma unroll
    for (int q = 0; q < NCH; ++q) {
      int idx = tid + q*256;
      if (idx < NIDX) {
        int r = idx >> 3, ch = idx & 7;
        int gp = p0 - PAD + r;
        uint4 v = make_uint4(0u,0u,0u,0u);
        if (gp >= 0 && gp < LSEQ) {
          v = *(const uint4*)(Raw + idx*16);
          v = bn_pack(v, s_sc, s_sh, cic + ch*8);
        }
        *(uint4*)(XsB + r*128 + ((ch*16) ^ ((r&7)<<4))) = v;
      }
    }
  };

  for (int cic = 0; cic < CIN; cic += 64) {
    __syncthreads();            // prev compute done with XsB; DMA long complete
    transform(cic);
    __syncthreads();            // XsB visible; Raw free for next chunk's DMA
    const bool nxtc = (cic + 64 < CIN);
    const int nc = cic + 64;

    const __hip_bfloat16* wch = wlane + cic;

    auto wfrag = [&](short8v (&dst)[2][MF], int tap) {
      #pragma unroll
      for (int kk = 0; kk < 2; ++kk) {
        #pragma unroll
        for (int mf = 0; mf < MF; ++mf) {
          dst[kk][mf] = *(const short8v*)(wch + ((size_t)tap*COUT + mf*16)*CIN + kk*32);
        }
      }
    };
    auto do_tap = [&](short8v (&cur)[2][MF], short8v (&nxt)[2][MF], int t) {
      if (t+1 < K) wfrag(nxt, t+1);       // prefetch next tap's weights
      if (nxtc && t < NCH) dma_one(nc, t); // interleave next-chunk DMA, 1 batch/tap
      __builtin_amdgcn_s_setprio(1);
      #pragma unroll
      for (int kk = 0; kk < 2; ++kk) {
        short8v bfr[NF];
        #pragma unroll
        for (int nf = 0; nf < NF; ++nf) {
          int rr = wn*WN_T + nf*16 + colp + t;
          bfr[nf] = *(const short8v*)(XsB + rr*128 + ((kk*64 + rgrp*16) ^ ((rr&7)<<4)));
        }
        #pragma unroll
        for (int mf = 0; mf < MF; ++mf) {
          #pragma unroll
          for (int nf = 0; nf < NF; ++nf) {
            acc[mf][nf] = __builtin_amdgcn_mfma_f32_16x16x32_bf16(cur[kk][mf], bfr[nf], acc[mf][nf], 0, 0, 0);
          }
        }
      }
      __builtin_amdgcn_s_setprio(0);
    };
    short8v afE[2][MF], afO[2][MF];
    wfrag(afE, 0);
    for (int t = 0; t < K; t += 2) {
      do_tap(afE, afO, t);
      if (t+1 < K) do_tap(afO, afE, t+1);
    }
    if (nxtc) {                            // leftover batches if K < NCH
      for (int q = K; q < NCH; ++q) dma_one(nc, q);
    }
  }

  // staged coalesced epilogue (co-half0 -> XsB, co-half1 -> Raw)
  __syncthreads();
  #pragma unroll
  for (int mf = 0; mf < MF; ++mf) {
    int co_rel = wm*WM_T + mf*16 + rgrp*4;
    int co_b = co0 + co_rel;
    float b0 = cb[co_b+0], b1 = cb[co_b+1], b2 = cb[co_b+2], b3 = cb[co_b+3];
    float s1v[4] = {0,0,0,0}, s2v[4] = {0,0,0,0};
    char* sbase = (co_rel*2 < 128) ? XsB : Raw;
    int cb2 = (co_rel*2) & 127;
    #pragma unroll
    for (int nf = 0; nf < NF; ++nf) {
      int pl = wn*WN_T + nf*16 + colp;
      float y0 = acc[mf][nf][0] + b0;
      float y1 = acc[mf][nf][1] + b1;
      float y2 = acc[mf][nf][2] + b2;
      float y3 = acc[mf][nf][3] + b3;
      ushort4 pk = make_ushort4(f2b(y0), f2b(y1), f2b(y2), f2b(y3));
      *(ushort4*)(sbase + pl*128 + (cb2 ^ ((pl&7)<<4))) = pk;
      s1v[0]+=y0; s1v[1]+=y1; s1v[2]+=y2; s1v[3]+=y3;
      s2v[0]+=y0*y0; s2v[1]+=y1*y1; s2v[2]+=y2*y2; s2v[3]+=y3*y3;
    }
    #pragma unroll
    for (int off = 1; off < 16; off <<= 1) {
      #pragma unroll
      for (int r = 0; r < 4; ++r) {
        s1v[r] += __shfl_xor(s1v[r], off, 64);
        s2v[r] += __shfl_xor(s2v[r], off, 64);
      }
    }
    if (colp == 0) {
      #pragma unroll
      for (int r = 0; r < 4; ++r) {
        atomicAdd(&S1[co_b+r], s1v[r]);
        atomicAdd(&S2[co_b+r], s2v[r]);
      }
    }
  }
  __syncthreads();
  constexpr int OW = BM/8;     // uint4 chunks per output row
  for (int idx = tid; idx < NPOS*OW; idx += 256) {
    int r = idx / OW, c16 = idx - r*OW;
    const char* sbase = (c16*16 < 128) ? XsB : Raw;
    int cbb = (c16*16) & 127;
    uint4 v = *(const uint4*)(sbase + r*128 + (cbb ^ ((r&7)<<4)));
    *(uint4*)(out + (brow + p0 + r)*COUT + co0 + c16*8) = v;
  }
}

#define CONV_ARGS const __hip_bfloat16* in, const __hip_bfloat16* wb, const float* cb, \
                  const float* S1p, const float* S2p, const float* g, const float* be, \
                  __hip_bfloat16* out, float* S1, float* S2

__global__ __launch_bounds__(256, 2) void conv_l1(CONV_ARGS){ conv_impl<64,64,5,64,256,32>(in,wb,cb,S1p,S2p,g,be,out,S1,S2); }
__global__ __launch_bounds__(256, 2) void conv_l2(CONV_ARGS){ conv_impl<64,128,15,128,256>(in,wb,cb,S1p,S2p,g,be,out,S1,S2); }
__global__ __launch_bounds__(256, 2) void conv_l3(CONV_ARGS){ conv_impl<128,128,15,128,256>(in,wb,cb,S1p,S2p,g,be,out,S1,S2); }
__global__ __launch_bounds__(256, 2) void conv_l4(CONV_ARGS){ conv_impl<128,256,25,128,256>(in,wb,cb,S1p,S2p,g,be,out,S1,S2); }
__global__ __launch_bounds__(256, 2) void conv_l5(CONV_ARGS){ conv_impl<256,256,25,128,256>(in,wb,cb,S1p,S2p,g,be,out,S1,S2); }

// ---------- feat+head fused: per-chunk channel sums -> partial GEMV -> atomic out ----------
// out = (sum_L relu(bn(a5)))/L @ W.T + bias, accumulated per 256-pos chunk.
__global__ __launch_bounds__(256)
void feat_head(const __hip_bfloat16* __restrict__ a,
               const float* __restrict__ S1, const float* __restrict__ S2,
               const float* __restrict__ g, const float* __restrict__ be,
               const float* __restrict__ wm, const float* __restrict__ bm,
               const float* __restrict__ wv, const float* __restrict__ bv,
               float* __restrict__ out)
{
  __shared__ float sfeat[256];
  const int b = blockIdx.y, chunk = blockIdx.x, c = threadIdx.x;
  const float invN = 1.f / 65536.f;
  float mm = S1[c] * invN;
  float var = fmaxf(S2[c] * invN - mm*mm, 0.f);
  float sc = g[c] / sqrtf(var + 1e-5f);
  float sh = be[c] - mm * sc;
  float s = 0.f;
  const __hip_bfloat16* p = a + ((size_t)b*LSEQ + chunk*256)*256 + c;
  #pragma unroll 4
  for (int i = 0; i < 256; ++i)
    s += fmaxf(fmaf(__bfloat162float(p[(size_t)i*256]), sc, sh), 0.f);
  sfeat[c] = s;
  __syncthreads();
  if (c < 128) {
    int sel = c >> 6, j = c & 63;
    const float* W = sel ? wv : wm;
    const float* bias = sel ? bv : bm;
    const float4* srow = (const float4*)sfeat;
    const float4* wr = (const float4*)(W + j*256);
    float acc = 0.f;
    #pragma unroll 4
    for (int q = 0; q < 64; ++q) {
      float4 a4 = srow[q], w4 = wr[q];
      acc += a4.x*w4.x + a4.y*w4.y + a4.z*w4.z + a4.w*w4.w;
    }
    acc *= (1.f/(float)LSEQ);
    if (chunk == 0) acc += bias[j];
    atomicAdd(&out[sel*2048 + b*64 + j], acc);
  }
}

extern "C" void kernel_launch(void* const* d_in, const int* in_sizes, int n_in,
                              void* d_out, int out_size, void* d_ws, size_t ws_size,
                              hipStream_t stream)
{
  (void)in_sizes; (void)n_in; (void)out_size; (void)ws_size;
  const float* x = (const float*)d_in[0];
  const float *cw[6], *cbp[6], *bg[6], *bb[6];
  for (int i = 0; i < 6; i++){
    cw[i]=(const float*)d_in[1+4*i]; cbp[i]=(const float*)d_in[2+4*i];
    bg[i]=(const float*)d_in[3+4*i]; bb[i]=(const float*)d_in[4+4*i];
  }
  const float* wmh=(const float*)d_in[25]; const float* bmh=(const float*)d_in[26];
  const float* wvh=(const float*)d_in[27]; const float* bvh=(const float*)d_in[28];

  char* ws = (char*)d_ws;
  size_t off = 0;
  float* h0 = (float*)(ws+off);            off += (size_t)NB*LSEQ*4;   // unused (kept for layout)
  __hip_bfloat16* bufA = (__hip_bfloat16*)(ws+off); off += (size_t)NB*LSEQ*256*2;
  __hip_bfloat16* bufB = (__hip_bfloat16*)(ws+off); off += (size_t)NB*LSEQ*256*2;
  __hip_bfloat16* wb1 = (__hip_bfloat16*)(ws+off); off += (size_t)5*64*64*2;
  __hip_bfloat16* wb2 = (__hip_bfloat16*)(ws+off); off += (size_t)15*128*64*2;
  __hip_bfloat16* wb3 = (__hip_bfloat16*)(ws+off); off += (size_t)15*128*128*2;
  __hip_bfloat16* wb4 = (__hip_bfloat16*)(ws+off); off += (size_t)25*256*128*2;
  __hip_bfloat16* wb5 = (__hip_bfloat16*)(ws+off); off += (size_t)25*256*256*2;
  float* stats = (float*)(ws+off);         off += 3072*4;
  float* S0p1  = (float*)(ws+off);         off += (size_t)NB*64*4;    // conv0 partials
  float* S0p2  = (float*)(ws+off);         off += (size_t)NB*64*4;
  float* S1 = stats; float* S2 = stats + 1536;
  (void)h0;

  // merged: zero stats + d_out, weight transpose, row preprocessing + conv0
  prep_row<<<908, 256, 0, stream>>>(x, cw[0], cbp[0],
                                    cw[1], cw[2], cw[3], cw[4], cw[5],
                                    wb1, wb2, wb3, wb4, wb5, stats, (float*)d_out,
                                    bufA, S0p1, S0p2);

  conv_l1<<<dim3(8,1,NB),256,0,stream>>>(
      bufA, wb1, cbp[1], S0p1, S0p2, bg[0], bb[0], bufB, S1+256, S2+256);

  conv_l2<<<dim3(8,1,NB),256,0,stream>>>(
      bufB, wb2, cbp[2], S1+256, S2+256, bg[1], bb[1], bufA, S1+512, S2+512);

  conv_l3<<<dim3(8,1,NB),256,0,stream>>>(
      bufA, wb3, cbp[3], S1+512, S2+512, bg[2], bb[2], bufB, S1+768, S2+768);

  conv_l4<<<dim3(8,2,NB),256,0,stream>>>(
      bufB, wb4, cbp[4], S1+768, S2+768, bg[3], bb[3], bufA, S1+1024, S2+1024);

  conv_l5<<<dim3(8,2,NB),256,0,stream>>>(
      bufA, wb5, cbp[5], S1+1024, S2+1024, bg[4], bb[4], bufB, S1+1280, S2+1280);

  feat_head<<<dim3(8, NB), 256, 0, stream>>>(bufB, S1+1280, S2+1280, bg[5], bb[5],
                                             wmh, bmh, wvh, bvh, (float*)d_out);
}

// Round 22
// 775.107 us; speedup vs baseline: 1.0715x; 1.0056x over previous
//
#include <hip/hip_runtime.h>
#include <hip/hip_bf16.h>

#define LSEQ 2048
#define NB 32

typedef __attribute__((ext_vector_type(8))) short short8v;
typedef __attribute__((ext_vector_type(4))) float float4v;

// ---------- dtype helpers ----------
__device__ __forceinline__ unsigned short f2b(float f){
  __hip_bfloat16 h = __float2bfloat16(f);
  return *reinterpret_cast<unsigned short*>(&h);
}
__device__ __forceinline__ float b2f_bits(unsigned short u){
  unsigned int x = ((unsigned int)u) << 16; return __uint_as_float(x);
}

__device__ __forceinline__ float wave_min(float v){
  #pragma unroll
  for (int off = 32; off; off >>= 1) v = fminf(v, __shfl_xor(v, off, 64));
  return v;
}

// apply BN(scale,shift)+relu to 8 bf16 packed in uint4, repack to bf16
__device__ __forceinline__ uint4 bn_pack(uint4 g, const float* sc, const float* sh, int cbase){
  union { uint4 u; unsigned short us[8]; } in_, out_;
  in_.u = g;
  #pragma unroll
  for (int j = 0; j < 8; ++j){
    float v = b2f_bits(in_.us[j]);
    v = fmaxf(fmaf(v, sc[cbase+j], sh[cbase+j]), 0.f);
    out_.us[j] = f2b(v);
  }
  return out_.u;
}

// async 16B global -> LDS
__device__ __forceinline__ void gl_lds16(const void* g, void* l){
  __builtin_amdgcn_global_load_lds(
      (const __attribute__((address_space(1))) void*)g,
      (__attribute__((address_space(3))) void*)l, 16, 0, 0);
}

// ---------- merged prep + row_prep + conv0 ----------
// blocks 0..43: zero stats + d_out; 44..875: weight transpose fp32->bf16 [t][co][ci];
// 876..907: row preprocessing (stats+find_peaks+normalize) + conv0 from LDS row,
//           conv0 stats written as per-batch PARTIALS (no atomics, no zero dep).
__global__ __launch_bounds__(256)
void prep_row(const float* __restrict__ x,
              const float* __restrict__ w0, const float* __restrict__ cb0,
              const float* __restrict__ w1, const float* __restrict__ w2,
              const float* __restrict__ w3, const float* __restrict__ w4,
              const float* __restrict__ w5,
              __hip_bfloat16* __restrict__ o1, __hip_bfloat16* __restrict__ o2,
              __hip_bfloat16* __restrict__ o3, __hip_bfloat16* __restrict__ o4,
              __hip_bfloat16* __restrict__ o5,
              float* __restrict__ zbuf, float* __restrict__ dout,
              __hip_bfloat16* __restrict__ c0out,
              float* __restrict__ S0p1, float* __restrict__ S0p2)
{
  __shared__ alignas(16) char pool[25600];
  const int blk = blockIdx.x, tid = threadIdx.x;

  if (blk < 876) {
    // ---- prep path ----
    int b = blk;
    if (b < 44) {
      int i = b*256 + tid;
      if (i < 3072) zbuf[i] = 0.f;     // conv1..5 stats
      if (i < 4096) dout[i] = 0.f;     // output accumulators (harness poisons d_out)
      return;
    }
    b -= 44;
    float* tile = (float*)pool;
    const float* w; __hip_bfloat16* o; int COUT, CIN, K, co;
    if      (b < 64)  { w=w1; o=o1; COUT=64;  CIN=64;  K=5;  co=b;     }
    else if (b < 192) { w=w2; o=o2; COUT=128; CIN=64;  K=15; co=b-64;  }
    else if (b < 320) { w=w3; o=o3; COUT=128; CIN=128; K=15; co=b-192; }
    else if (b < 576) { w=w4; o=o4; COUT=256; CIN=128; K=25; co=b-320; }
    else              { w=w5; o=o5; COUT=256; CIN=256; K=25; co=b-576; }
    const int n = CIN * K;
    const float* src = w + (size_t)co * n;
    for (int i = tid; i < n; i += 256) tile[i] = src[i];        // tile[ci*K + t]
    __syncthreads();
    for (int i = tid; i < n; i += 256) {
      int t = i / CIN, ci = i - t*CIN;
      o[((size_t)t*COUT + co)*CIN + ci] = __float2bfloat16(tile[ci*K + t]);
    }
    return;
  }

  // ---- row path ----
  const int b = blk - 876;
  const int lane = tid & 63, wid = tid >> 6;
  float* xs_raw            = (float*)(pool + 0);          // (2048+18) floats
  unsigned char* st_raw    = (unsigned char*)(pool + 8264);
  unsigned char* peaks     = (unsigned char*)(pool + 10332);
  short* s_cand            = (short*)(pool + 12380);
  short* s_kept            = (short*)(pool + 14428);
  float* sw                = (float*)(pool + 14940);      // 320
  float* sb                = (float*)(pool + 16220);      // 64
  float (*redA)[64]        = (float(*)[64])(pool + 16476);
  float (*redB)[64]        = (float(*)[64])(pool + 17500);
  float* s_redA            = (float*)(pool + 18524);      // 4
  float* s_redB            = (float*)(pool + 18540);      // 4
  float* s_sc3             = (float*)(pool + 18556);      // mx, mean, std
  int*   s_int             = (int*)(pool + 18568);        // flag, cnt, kcnt
  float* xsp = xs_raw + 9;
  unsigned char* stp = st_raw + 9;

  const float* xr = x + (size_t)b * LSEQ;
  for (int i = tid; i < LSEQ; i += 256) xsp[i] = xr[i];
  for (int i = tid; i < 18; i += 256) {
    xs_raw[(i < 9) ? i : (LSEQ + i)] = -__builtin_inff();
    st_raw[(i < 9) ? i : (LSEQ + i)] = 2;
  }
  for (int i = tid; i < 320; i += 256) sw[i] = w0[i];
  if (tid < 64) sb[tid] = cb0[tid];
  if (tid == 0) { s_int[1] = 0; s_int[2] = 0; }
  __syncthreads();

  float vmax = -__builtin_inff(), vsum = 0.f;
  for (int i = tid; i < LSEQ; i += 256) { float v = xsp[i]; vmax = fmaxf(vmax, v); vsum += v; }
  #pragma unroll
  for (int off = 32; off; off >>= 1){
    vmax = fmaxf(vmax, __shfl_xor(vmax, off, 64));
    vsum += __shfl_xor(vsum, off, 64);
  }
  if (lane == 0){ s_redA[wid] = vmax; s_redB[wid] = vsum; }
  __syncthreads();
  if (tid == 0){
    s_sc3[0] = fmaxf(fmaxf(s_redA[0], s_redA[1]), fmaxf(s_redA[2], s_redA[3]));
    s_sc3[1] = (s_redB[0]+s_redB[1]+s_redB[2]+s_redB[3]) * (1.f/(float)LSEQ);
  }
  __syncthreads();
  const float m = s_sc3[1], mx = s_sc3[0];

  float vss = 0.f;
  for (int i = tid; i < LSEQ; i += 256){ float d = xsp[i]-m; vss += d*d; }
  #pragma unroll
  for (int off = 32; off; off >>= 1) vss += __shfl_xor(vss, off, 64);
  if (lane == 0) s_redA[wid] = vss;
  __syncthreads();
  if (tid == 0) s_sc3[2] = sqrtf((s_redA[0]+s_redA[1]+s_redA[2]+s_redA[3]) / (float)(LSEQ-1));
  __syncthreads();
  const float sd = s_sc3[2];

  const float hthr = 0.1f * mx;
  for (int i = tid; i < LSEQ; i += 256) {
    unsigned char c = 2;
    if (i >= 1 && i <= LSEQ-2) {
      float v = xsp[i];
      if ((v > xsp[i-1]) && (v > xsp[i+1]) && (v >= hthr)) {
        c = 0;
        int s = atomicAdd(&s_int[1], 1);
        if (s < 1024) s_cand[s] = (short)i;
      }
    }
    stp[i] = c; peaks[i] = 0;
  }
  __syncthreads();
  const int cnt = (s_int[1] < 1024) ? s_int[1] : 1024;

  for (int round = 0; round < 1024; ++round) {
    if (tid == 0) s_int[0] = 0;
    __syncthreads();
    int und = 0;
    for (int q = tid; q < cnt; q += 256) {
      int i = s_cand[q];
      if (stp[i] == 0) {
        float xi = xsp[i];
        bool anyK = false, allD = true;
        #pragma unroll
        for (int o = -9; o <= 9; ++o) {
          if (o == 0) continue;
          unsigned char s = stp[i+o];
          float xj = xsp[i+o];
          bool hi = (xj > xi) || (xj == xi && o < 0);
          anyK = anyK || (hi && s == 1);
          allD = allD && ((!hi) || s == 2);
        }
        unsigned char ns = anyK ? 2 : (allD ? 1 : 0);
        if (ns) stp[i] = ns; else und = 1;
      }
    }
    if (und) s_int[0] = 1;
    __syncthreads();
    if (!s_int[0]) break;
  }

  for (int q = tid; q < cnt; q += 256) {
    int i = s_cand[q];
    if (stp[i] == 1) { int s = atomicAdd(&s_int[2], 1); s_kept[s] = (short)i; }
  }
  __syncthreads();
  const int M = s_int[2];
  const float pthr = 0.05f * mx;

  for (int c = wid; c < M; c += 4) {
    int p = s_kept[c]; float xp = xsp[p];
    float lm = xp; bool done = false;
    for (int s = 0; !done; ++s) {
      int idx = p - 64*(s+1) + lane;
      float v = (idx >= 0) ? xsp[idx] : -__builtin_inff();
      unsigned long long mk = __ballot(v > xp);
      if (mk) {
        int hb = 63 - __builtin_clzll(mk);
        lm = fminf(lm, (lane > hb) ? v : __builtin_inff());
        done = true;
      } else {
        lm = fminf(lm, (idx >= 0) ? v : __builtin_inff());
        done = (p - 64*(s+1) <= 0);
      }
    }
    float lmin = wave_min(lm);
    float rm = xp; done = false;
    for (int s = 0; !done; ++s) {
      int idx = p + 1 + 64*s + lane;
      float v = (idx < LSEQ) ? xsp[idx] : -__builtin_inff();
      unsigned long long mk = __ballot(v > xp);
      if (mk) {
        int lb_ = __builtin_ctzll(mk);
        rm = fminf(rm, (lane < lb_) ? v : __builtin_inff());
        done = true;
      } else {
        rm = fminf(rm, (idx < LSEQ) ? v : __builtin_inff());
        done = (p + 64 + 64*s >= LSEQ-1);
      }
    }
    float rmin = wave_min(rm);
    if (lane == 0 && (xp - fmaxf(lmin, rmin)) >= pthr) peaks[p] = 1;
  }
  __syncthreads();

  // normalize in place
  const float inv = 1.f / (sd + 1e-5f);
  for (int i = tid; i < LSEQ; i += 256) {
    float w_ = 1.f + 0.1f * (float)peaks[i];
    xsp[i] = (w_ * (xsp[i] - m)) * inv;
  }
  __syncthreads();

  // conv0 from LDS row: thread owns co = tid&63, positions pgrp,pgrp+4,...
  const int co = tid & 63, pgrp = tid >> 6;
  float wk0 = sw[co*5+0], wk1 = sw[co*5+1], wk2 = sw[co*5+2],
        wk3 = sw[co*5+3], wk4 = sw[co*5+4];
  const float bias = sb[co];
  float s1 = 0.f, s2 = 0.f;
  __hip_bfloat16* orow = c0out + (size_t)b * LSEQ * 64 + co;
  for (int pos = pgrp; pos < LSEQ; pos += 4) {
    float x0 = (pos-2 >= 0)   ? xsp[pos-2] : 0.f;
    float x1 = (pos-1 >= 0)   ? xsp[pos-1] : 0.f;
    float x2 = xsp[pos];
    float x3 = (pos+1 < LSEQ) ? xsp[pos+1] : 0.f;
    float x4 = (pos+2 < LSEQ) ? xsp[pos+2] : 0.f;
    float y = bias;
    y = fmaf(wk0, x0, y);
    y = fmaf(wk1, x1, y);
    y = fmaf(wk2, x2, y);
    y = fmaf(wk3, x3, y);
    y = fmaf(wk4, x4, y);
    orow[(size_t)pos*64] = __float2bfloat16(y);
    s1 += y; s2 += y*y;
  }
  redA[pgrp][co] = s1; redB[pgrp][co] = s2;
  __syncthreads();
  if (tid < 64) {
    float a  = redA[0][tid]+redA[1][tid]+redA[2][tid]+redA[3][tid];
    float bb = redB[0][tid]+redB[1][tid]+redB[2][tid]+redB[3][tid];
    S0p1[b*64 + tid] = a;      // per-batch partials, no atomics
    S0p2[b*64 + tid] = bb;
  }
}

// ---------- MFMA implicit-GEMM conv, 16x16x32, tap-interleaved async DMA ----------
// NPART: number of partial-sum rows in S1p/S2p ([NPART][CIN]); 1 = plain.
template<int CIN, int COUT, int K, int BM, int NPOS, int NPART = 1>
__device__ __forceinline__
void conv_impl(const __hip_bfloat16* __restrict__ in,
               const __hip_bfloat16* __restrict__ wb,
               const float* __restrict__ cb,
               const float* __restrict__ S1p, const float* __restrict__ S2p,
               const float* __restrict__ g, const float* __restrict__ be,
               __hip_bfloat16* __restrict__ out,
               float* __restrict__ S1, float* __restrict__ S2)
{
  constexpr int PAD = K/2, XR = NPOS + K - 1;
  constexpr int WM_T = BM/2, MF = WM_T/16;
  constexpr int WN_T = NPOS/2, NF = WN_T/16;
  constexpr int NIDX = XR*8;
  constexpr int NCH = (NIDX + 255)/256;

  __shared__ float s_sc[CIN], s_sh[CIN];
  __shared__ alignas(16) char XsB[XR*128];       // swizzled [pos][64ci]
  __shared__ alignas(16) char Raw[NCH*4096];     // linear DMA landing zone

  const int tid = threadIdx.x;
  const int lane = tid & 63;
  const int wid = tid >> 6;
  const int wm = wid >> 1, wn = wid & 1;
  const int b = blockIdx.z;
  const int p0 = blockIdx.x * NPOS;
  const int co0 = blockIdx.y * BM;
  const int colp = lane & 15, rgrp = lane >> 4;

  const size_t brow = (size_t)b * LSEQ;

  auto dma_one = [&](int cic, int q){
    int idx = tid + q*256;
    int r = idx >> 3, ch = idx & 7;
    int gp = p0 - PAD + r;
    int gpc = gp < 0 ? 0 : (gp > LSEQ-1 ? LSEQ-1 : gp);
    gl_lds16(in + (brow + gpc)*CIN + cic + ch*8, Raw + idx*16);
  };
  auto issue_dma = [&](int cic){
    #pragma unroll
    for (int q = 0; q < NCH; ++q) dma_one(cic, q);
  };

  issue_dma(0);     // first chunk's DMA flies under the BN-finalize preamble

  const float invN = 1.f / 65536.f;
  for (int i = tid; i < CIN; i += 256) {
    float a = 0.f, bq = 0.f;
    for (int p = 0; p < NPART; ++p) { a += S1p[p*CIN + i]; bq += S2p[p*CIN + i]; }
    float mm = a * invN;
    float var = fmaxf(bq * invN - mm*mm, 0.f);
    float sc = g[i] / sqrtf(var + 1e-5f);
    s_sc[i] = sc;
    s_sh[i] = be[i] - mm * sc;
  }

  float4v acc[MF][NF];
  #pragma unroll
  for (int mf = 0; mf < MF; ++mf) {
    #pragma unroll
    for (int nf = 0; nf < NF; ++nf) acc[mf][nf] = (float4v){0.f,0.f,0.f,0.f};
  }

  const __hip_bfloat16* wlane = wb + ((size_t)(co0 + wm*WM_T + colp))*CIN + rgrp*8;

  auto transform = [&](int cic){
    #pragma unroll
    for (int q = 0; q < NCH; ++q) {
      int idx = tid + q*256;
      if (idx < NIDX) {
        int r = idx >> 3, ch = idx & 7;
        int gp = p0 - PAD + r;
        uint4 v = make_uint4(0u,0u,0u,0u);
        if (gp >= 0 && gp < LSEQ) {
          v = *(const uint4*)(Raw + idx*16);
          v = bn_pack(v, s_sc, s_sh, cic + ch*8);
        }
        *(uint4*)(XsB + r*128 + ((ch*16) ^ ((r&7)<<4))) = v;
      }
    }
  };

  for (int cic = 0; cic < CIN; cic += 64) {
    __syncthreads();            // prev compute done with XsB; DMA long complete
    transform(cic);
    __syncthreads();            // XsB visible; Raw free for next chunk's DMA
    const bool nxtc = (cic + 64 < CIN);
    const int nc = cic + 64;

    const __hip_bfloat16* wch = wlane + cic;

    auto wfrag = [&](short8v (&dst)[2][MF], int tap) {
      #pragma unroll
      for (int kk = 0; kk < 2; ++kk) {
        #pragma unroll
        for (int mf = 0; mf < MF; ++mf) {
          dst[kk][mf] = *(const short8v*)(wch + ((size_t)tap*COUT + mf*16)*CIN + kk*32);
        }
      }
    };
    auto do_tap = [&](short8v (&cur)[2][MF], short8v (&nxt)[2][MF], int t) {
      if (t+1 < K) wfrag(nxt, t+1);       // prefetch next tap's weights
      if (nxtc && t < NCH) dma_one(nc, t); // interleave next-chunk DMA, 1 batch/tap
      __builtin_amdgcn_s_setprio(1);
      #pragma unroll
      for (int kk = 0; kk < 2; ++kk) {
        short8v bfr[NF];
        #pragma unroll
        for (int nf = 0; nf < NF; ++nf) {
          int rr = wn*WN_T + nf*16 + colp + t;
          bfr[nf] = *(const short8v*)(XsB + rr*128 + ((kk*64 + rgrp*16) ^ ((rr&7)<<4)));
        }
        #pragma unroll
        for (int mf = 0; mf < MF; ++mf) {
          #pragma unroll
          for (int nf = 0; nf < NF; ++nf) {
            acc[mf][nf] = __builtin_amdgcn_mfma_f32_16x16x32_bf16(cur[kk][mf], bfr[nf], acc[mf][nf], 0, 0, 0);
          }
        }
      }
      __builtin_amdgcn_s_setprio(0);
    };
    short8v afE[2][MF], afO[2][MF];
    wfrag(afE, 0);
    for (int t = 0; t < K; t += 2) {
      do_tap(afE, afO, t);
      if (t+1 < K) do_tap(afO, afE, t+1);
    }
    if (nxtc) {                            // leftover batches if K < NCH
      for (int q = K; q < NCH; ++q) dma_one(nc, q);
    }
  }

  // staged coalesced epilogue (co-half0 -> XsB, co-half1 -> Raw)
  __syncthreads();
  #pragma unroll
  for (int mf = 0; mf < MF; ++mf) {
    int co_rel = wm*WM_T + mf*16 + rgrp*4;
    int co_b = co0 + co_rel;
    float b0 = cb[co_b+0], b1 = cb[co_b+1], b2 = cb[co_b+2], b3 = cb[co_b+3];
    float s1v[4] = {0,0,0,0}, s2v[4] = {0,0,0,0};
    char* sbase = (co_rel*2 < 128) ? XsB : Raw;
    int cb2 = (co_rel*2) & 127;
    #pragma unroll
    for (int nf = 0; nf < NF; ++nf) {
      int pl = wn*WN_T + nf*16 + colp;
      float y0 = acc[mf][nf][0] + b0;
      float y1 = acc[mf][nf][1] + b1;
      float y2 = acc[mf][nf][2] + b2;
      float y3 = acc[mf][nf][3] + b3;
      ushort4 pk = make_ushort4(f2b(y0), f2b(y1), f2b(y2), f2b(y3));
      *(ushort4*)(sbase + pl*128 + (cb2 ^ ((pl&7)<<4))) = pk;
      s1v[0]+=y0; s1v[1]+=y1; s1v[2]+=y2; s1v[3]+=y3;
      s2v[0]+=y0*y0; s2v[1]+=y1*y1; s2v[2]+=y2*y2; s2v[3]+=y3*y3;
    }
    #pragma unroll
    for (int off = 1; off < 16; off <<= 1) {
      #pragma unroll
      for (int r = 0; r < 4; ++r) {
        s1v[r] += __shfl_xor(s1v[r], off, 64);
        s2v[r] += __shfl_xor(s2v[r], off, 64);
      }
    }
    if (colp == 0) {
      #pragma unroll
      for (int r = 0; r < 4; ++r) {
        atomicAdd(&S1[co_b+r], s1v[r]);
        atomicAdd(&S2[co_b+r], s2v[r]);
      }
    }
  }
  __syncthreads();
  constexpr int OW = BM/8;     // uint4 chunks per output row
  for (int idx = tid; idx < NPOS*OW; idx += 256) {
    int r = idx / OW, c16 = idx - r*OW;
    const char* sbase = (c16*16 < 128) ? XsB : Raw;
    int cbb = (c16*16) & 127;
    uint4 v = *(const uint4*)(sbase + r*128 + (cbb ^ ((r&7)<<4)));
    *(uint4*)(out + (brow + p0 + r)*COUT + co0 + c16*8) = v;
  }
}

#define CONV_ARGS const __hip_bfloat16* in, const __hip_bfloat16* wb, const float* cb, \
                  const float* S1p, const float* S2p, const float* g, const float* be, \
                  __hip_bfloat16* out, float* S1, float* S2

__global__ __launch_bounds__(256, 2) void conv_l1(CONV_ARGS){ conv_impl<64,64,5,64,256,32>(in,wb,cb,S1p,S2p,g,be,out,S1,S2); }
__global__ __launch_bounds__(256, 2) void conv_l2(CONV_ARGS){ conv_impl<64,128,15,128,256>(in,wb,cb,S1p,S2p,g,be,out,S1,S2); }
__global__ __launch_bounds__(256, 2) void conv_l3(CONV_ARGS){ conv_impl<128,128,15,128,256>(in,wb,cb,S1p,S2p,g,be,out,S1,S2); }
__global__ __launch_bounds__(256, 2) void conv_l4(CONV_ARGS){ conv_impl<128,256,25,128,256>(in,wb,cb,S1p,S2p,g,be,out,S1,S2); }
__global__ __launch_bounds__(256, 2) void conv_l5(CONV_ARGS){ conv_impl<256,256,25,128,256>(in,wb,cb,S1p,S2p,g,be,out,S1,S2); }

// ---------- feat+head fused: per-chunk channel sums -> partial GEMV -> atomic out ----------
// out = (sum_L relu(bn(a5)))/L @ W.T + bias, accumulated per 256-pos chunk.
__global__ __launch_bounds__(256)
void feat_head(const __hip_bfloat16* __restrict__ a,
               const float* __restrict__ S1, const float* __restrict__ S2,
               const float* __restrict__ g, const float* __restrict__ be,
               const float* __restrict__ wm, const float* __restrict__ bm,
               const float* __restrict__ wv, const float* __restrict__ bv,
               float* __restrict__ out)
{
  __shared__ float sfeat[256];
  const int b = blockIdx.y, chunk = blockIdx.x, c = threadIdx.x;
  const float invN = 1.f / 65536.f;
  float mm = S1[c] * invN;
  float var = fmaxf(S2[c] * invN - mm*mm, 0.f);
  float sc = g[c] / sqrtf(var + 1e-5f);
  float sh = be[c] - mm * sc;
  float s = 0.f;
  const __hip_bfloat16* p = a + ((size_t)b*LSEQ + chunk*256)*256 + c;
  #pragma unroll 4
  for (int i = 0; i < 256; ++i)
    s += fmaxf(fmaf(__bfloat162float(p[(size_t)i*256]), sc, sh), 0.f);
  sfeat[c] = s;
  __syncthreads();
  if (c < 128) {
    int sel = c >> 6, j = c & 63;
    const float* W = sel ? wv : wm;
    const float* bias = sel ? bv : bm;
    const float4* srow = (const float4*)sfeat;
    const float4* wr = (const float4*)(W + j*256);
    float acc = 0.f;
    #pragma unroll 4
    for (int q = 0; q < 64; ++q) {
      float4 a4 = srow[q], w4 = wr[q];
      acc += a4.x*w4.x + a4.y*w4.y + a4.z*w4.z + a4.w*w4.w;
    }
    acc *= (1.f/(float)LSEQ);
    if (chunk == 0) acc += bias[j];
    atomicAdd(&out[sel*2048 + b*64 + j], acc);
  }
}

extern "C" void kernel_launch(void* const* d_in, const int* in_sizes, int n_in,
                              void* d_out, int out_size, void* d_ws, size_t ws_size,
                              hipStream_t stream)
{
  (void)in_sizes; (void)n_in; (void)out_size; (void)ws_size;
  const float* x = (const float*)d_in[0];
  const float *cw[6], *cbp[6], *bg[6], *bb[6];
  for (int i = 0; i < 6; i++){
    cw[i]=(const float*)d_in[1+4*i]; cbp[i]=(const float*)d_in[2+4*i];
    bg[i]=(const float*)d_in[3+4*i]; bb[i]=(const float*)d_in[4+4*i];
  }
  const float* wmh=(const float*)d_in[25]; const float* bmh=(const float*)d_in[26];
  const float* wvh=(const float*)d_in[27]; const float* bvh=(const float*)d_in[28];

  char* ws = (char*)d_ws;
  size_t off = 0;
  float* h0 = (float*)(ws+off);            off += (size_t)NB*LSEQ*4;   // unused (kept for layout)
  __hip_bfloat16* bufA = (__hip_bfloat16*)(ws+off); off += (size_t)NB*LSEQ*256*2;
  __hip_bfloat16* bufB = (__hip_bfloat16*)(ws+off); off += (size_t)NB*LSEQ*256*2;
  __hip_bfloat16* wb1 = (__hip_bfloat16*)(ws+off); off += (size_t)5*64*64*2;
  __hip_bfloat16* wb2 = (__hip_bfloat16*)(ws+off); off += (size_t)15*128*64*2;
  __hip_bfloat16* wb3 = (__hip_bfloat16*)(ws+off); off += (size_t)15*128*128*2;
  __hip_bfloat16* wb4 = (__hip_bfloat16*)(ws+off); off += (size_t)25*256*128*2;
  __hip_bfloat16* wb5 = (__hip_bfloat16*)(ws+off); off += (size_t)25*256*256*2;
  float* stats = (float*)(ws+off);         off += 3072*4;
  float* S0p1  = (float*)(ws+off);         off += (size_t)NB*64*4;    // conv0 partials
  float* S0p2  = (float*)(ws+off);         off += (size_t)NB*64*4;
  float* S1 = stats; float* S2 = stats + 1536;
  (void)h0;

  // merged: zero stats + d_out, weight transpose, row preprocessing + conv0
  prep_row<<<908, 256, 0, stream>>>(x, cw[0], cbp[0],
                                    cw[1], cw[2], cw[3], cw[4], cw[5],
                                    wb1, wb2, wb3, wb4, wb5, stats, (float*)d_out,
                                    bufA, S0p1, S0p2);

  conv_l1<<<dim3(8,1,NB),256,0,stream>>>(
      bufA, wb1, cbp[1], S0p1, S0p2, bg[0], bb[0], bufB, S1+256, S2+256);

  conv_l2<<<dim3(8,1,NB),256,0,stream>>>(
      bufB, wb2, cbp[2], S1+256, S2+256, bg[1], bb[1], bufA, S1+512, S2+512);

  conv_l3<<<dim3(8,1,NB),256,0,stream>>>(
      bufA, wb3, cbp[3], S1+512, S2+512, bg[2], bb[2], bufB, S1+768, S2+768);

  conv_l4<<<dim3(8,2,NB),256,0,stream>>>(
      bufB, wb4, cbp[4], S1+768, S2+768, bg[3], bb[3], bufA, S1+1024, S2+1024);

  conv_l5<<<dim3(8,2,NB),256,0,stream>>>(
      bufA, wb5, cbp[5], S1+1024, S2+1024, bg[4], bb[4], bufB, S1+1280, S2+1280);

  feat_head<<<dim3(8, NB), 256, 0, stream>>>(bufB, S1+1280, S2+1280, bg[5], bb[5],
                                             wmh, bmh, wvh, bvh, (float*)d_out);
}